// Round 10
// baseline (656.958 us; speedup 1.0000x reference)
//
#include <hip/hip_runtime.h>
#include <hip/hip_bf16.h>

#define NSP   20000
#define NSPAT 10000
#define ESS   160000
#define EBIP  320000
#define ESP   320000

static inline int cdiv_host(long a, long b) { return (int)((a + b - 1) / b); }

__device__ __forceinline__ float wave_red_sum(float p) {
#pragma unroll
  for (int m = 32; m >= 1; m >>= 1) p += __shfl_xor(p, m, 64);
  return p;
}

__device__ __forceinline__ float bf2f(unsigned short u) {
  return __uint_as_float(((unsigned int)u) << 16);
}
__device__ __forceinline__ unsigned short f2bf(float f) {
  unsigned int u = __float_as_uint(f);
  unsigned int r = (u + 0x7FFF + ((u >> 16) & 1)) >> 16;  // RN-even
  return (unsigned short)r;
}

// ---------------------------------------------------------------------------
// combined prep: spc96 = [mean|std|vis] (NSP*96) and h0 = [spat_x|spat_g]
// (NSPAT*16).  Mask mode from *flag (0=int32, 1=bytes, 2=float).
// ---------------------------------------------------------------------------
__global__ void build_pre_kernel(const float* __restrict__ mean, const float* __restrict__ stdv,
                                 const void* __restrict__ mask, const int* __restrict__ flag,
                                 const float* __restrict__ sx, const float* __restrict__ sg,
                                 float* __restrict__ spc96, float* __restrict__ h0) {
  const long totA = (long)NSP * 96;
  const long totB = (long)NSPAT * 16;
  int mode = *flag;
  for (long i = (long)blockIdx.x * blockDim.x + threadIdx.x; i < totA + totB;
       i += (long)gridDim.x * blockDim.x) {
    if (i < totA) {
      int n = (int)(i / 96), c = (int)(i % 96);
      float v;
      if (c < 32) v = mean[(long)n * 32 + c];
      else if (c < 64) v = stdv[(long)n * 32 + (c - 32)];
      else {
        long j = (long)n * 32 + (c - 64);
        int mv;
        if (mode == 0) mv = ((const int*)mask)[j];
        else if (mode == 2) mv = (((const float*)mask)[j] != 0.0f);
        else mv = (int)((const unsigned char*)mask)[j];
        v = mv ? 0.f : 1.f;   // vis = ~mask
      }
      spc96[i] = v;
    } else {
      long k = i - totA;
      int n = (int)(k / 16), c = (int)(k % 16);
      h0[k] = (c < 12) ? sx[(long)n * 12 + c] : sg[(long)n * 4 + (c - 12)];
    }
  }
}

// ---------------------------------------------------------------------------
// CSR build, 8-way partitioned atomics.  Partition p = (combined_i >> 8) & 7.
// ---------------------------------------------------------------------------
__global__ void count3_kernel(
    const int* c1, int E1, int* cp1, int* rnk1, int n1,
    const int* c2, int E2, int* cp2, int* rnk2, int n2,
    const int* c3, int E3, int* cp3, int* rnk3, int n3) {
  int total = E1 + E2 + E3;
  for (int i = blockIdx.x * blockDim.x + threadIdx.x; i < total; i += gridDim.x * blockDim.x) {
    int p = (i >> 8) & 7;
    if (i < E1) {
      int d = c1[i]; rnk1[i] = atomicAdd(&cp1[p * n1 + d], 1);
    } else if (i < E1 + E2) {
      int j = i - E1;
      int d = c2[j]; rnk2[j] = atomicAdd(&cp2[p * n2 + d], 1);
    } else {
      int j = i - E1 - E2;
      int d = c3[j]; rnk3[j] = atomicAdd(&cp3[p * n3 + d], 1);
    }
  }
}

// scan + inline partition-merge: converts cp[p*n+d] to per-partition exclusive
// offsets and writes exclusive prefix ptr[] (ptr[n] = total).
__global__ __launch_bounds__(1024) void scan3_kernel(
    int* cpA, int nA, int* ptrA,
    int* cpB, int nB, int* ptrB,
    int* cpC, int nC, int* ptrC) {
  int* cp; int n; int* ptr;
  if (blockIdx.x == 0) { cp = cpA; n = nA; ptr = ptrA; }
  else if (blockIdx.x == 1) { cp = cpB; n = nB; ptr = ptrB; }
  else { cp = cpC; n = nC; ptr = ptrC; }
  __shared__ int part[1024];
  int t = threadIdx.x;
  int ch = (n + 1023) / 1024;
  int beg = t * ch, end = min(beg + ch, n);
  int s = 0;
  for (int i = beg; i < end; ++i) {
    int tot = 0;
#pragma unroll
    for (int p = 0; p < 8; ++p) { int v = cp[p * n + i]; cp[p * n + i] = tot; tot += v; }
    ptr[i] = tot;           // stash node total
    s += tot;
  }
  part[t] = s;
  __syncthreads();
  for (int off = 1; off < 1024; off <<= 1) {
    int v = (t >= off) ? part[t - off] : 0;
    __syncthreads();
    part[t] += v;
    __syncthreads();
  }
  int run = (t == 0) ? 0 : part[t - 1];
  for (int i = beg; i < end; ++i) { int tot = ptr[i]; ptr[i] = run; run += tot; }
  if (t == 1023) ptr[n] = part[1023];
}

__global__ void scatter3_kernel(
    const int* r1, const int* c1, const float* e1, int E1, const int* p1, const int* cp1, const int* k1, int n1, int* s1, float* a1,
    const int* r2, const int* c2, const float* e2, int E2, const int* p2, const int* cp2, const int* k2, int n2, int* s2, float* a2,
    const int* r3, const int* c3, const float* e3, int E3, const int* p3, const int* cp3, const int* k3, int n3, int* s3, float* a3) {
  int total = E1 + E2 + E3;
  for (int i = blockIdx.x * blockDim.x + threadIdx.x; i < total; i += gridDim.x * blockDim.x) {
    int p = (i >> 8) & 7;
    if (i < E1) {
      int d = c1[i];
      int pos = p1[d] + cp1[p * n1 + d] + k1[i];
      s1[pos] = r1[i]; a1[pos] = e1[i];
    } else if (i < E1 + E2) {
      int j = i - E1;
      int d = c2[j];
      int pos = p2[d] + cp2[p * n2 + d] + k2[j];
      s2[pos] = r2[j]; a2[pos] = e2[j];
    } else {
      int j = i - E1 - E2;
      int d = c3[j];
      int pos = p3[d] + cp3[p * n3 + d] + k3[j];
      s3[pos] = r3[j]; a3[pos] = e3[j];
    }
  }
}

// loop_ea = mean of incoming edge_attr, from contiguous CSR cea
__global__ void leafin_csr2(const int* ptrA, const float* ceaA, int nA, float* leaA,
                            const int* ptrB, const float* ceaB, int nB, float* leaB) {
  int i = blockIdx.x * blockDim.x + threadIdx.x;
  if (i >= nA + nB) return;
  const int* ptr; const float* cea; float* lea; int d;
  if (i < nA) { ptr = ptrA; cea = ceaA; lea = leaA; d = i; }
  else { ptr = ptrB; cea = ceaB; lea = leaB; d = i - nA; }
  int e0 = ptr[d], e1 = ptr[d + 1];
  float s = 0.f;
  for (int e = e0; e < e1; ++e) s += cea[e];
  lea[d] = s / (float)max(e1 - e0, 1);
}

// dot_e[h] per layer (blocks 0..4) + mask-format detect (block 5, 64 lanes)
__global__ void dote_all_kernel(const float* __restrict__ We0, const float* __restrict__ ae0,
                                const float* __restrict__ We1, const float* __restrict__ ae1,
                                const float* __restrict__ Web, const float* __restrict__ aeb,
                                const float* __restrict__ We2, const float* __restrict__ ae2,
                                const float* __restrict__ We3, const float* __restrict__ ae3,
                                const unsigned int* __restrict__ mask,
                                float* __restrict__ dotes, int* __restrict__ flag) {
  int b = blockIdx.x, t = threadIdx.x;
  if (b == 5) {
    if (t < 64) {
      unsigned int w0 = mask[t], w1 = mask[t + 64], w2 = mask[t + 128], w3 = mask[t + 192];
      bool ai = (w0 <= 1u) && (w1 <= 1u) && (w2 <= 1u) && (w3 <= 1u);
      auto okf = [](unsigned int w) { return w == 0u || w == 0x3f800000u; };
      bool af = okf(w0) && okf(w1) && okf(w2) && okf(w3);
      unsigned long long bi = __ballot(ai), bf = __ballot(af);
      if (t == 0) *flag = (bi == ~0ull) ? 0 : ((bf == ~0ull) ? 2 : 1);
    }
    return;
  }
  const float *We, *ae;
  int n, off;
  switch (b) {
    case 0: We = We0; ae = ae0; n = 256; off = 0; break;
    case 1: We = We1; ae = ae1; n = 256; off = 4; break;
    case 2: We = Web; ae = aeb; n = 64;  off = 8; break;
    case 3: We = We2; ae = ae2; n = 256; off = 12; break;
    default: We = We3; ae = ae3; n = 256; off = 16; break;
  }
  if (t < n) {
    float p = wave_red_sum(We[t] * ae[t]);
    if ((t & 63) == 0) dotes[off + (t >> 6)] = p;
  }
}

struct XSrc { const float* p[5]; int w[5]; int n; };

// ---------------------------------------------------------------------------
// NOUT=64 projection, tiled: BR=32 rows/block, KC=32.  4 cols x 2 rows per
// thread.  mode: 0 = bias (skip store if Y null), 1 = bias+relu,
// 2 = final split (mean | softplus+eps).  a_s/a_d: H=1 dots.
// ---------------------------------------------------------------------------
__global__ __launch_bounds__(256) void proj64_kernel(
    XSrc xsrc, int M, int K,
    const float* __restrict__ W, const float* __restrict__ bias, int mode,
    const float* __restrict__ a_s, const float* __restrict__ a_d,
    float* __restrict__ al_s, float* __restrict__ al_d,
    float* __restrict__ Y, float* __restrict__ Y2) {
  constexpr int KC = 32;
  constexpr int BR = 32;
  constexpr int KCP = 36;
  __shared__ float wl[KC * 64];
  __shared__ float xl[BR * KCP];

  int t = threadIdx.x;
  int cg = t & 15, rg = t >> 4;
  int c0 = cg * 4;
  long row0 = (long)blockIdx.x * BR;

  float acc[2][4];
#pragma unroll
  for (int r = 0; r < 2; ++r)
#pragma unroll
    for (int j = 0; j < 4; ++j) acc[r][j] = 0.f;

  for (int k0 = 0; k0 < K; k0 += KC) {
    int seg = 0; int base = 0;
    while (k0 >= base + xsrc.w[seg]) { base += xsrc.w[seg]; ++seg; }
    const float* Xp = xsrc.p[seg];
    int stride = xsrc.w[seg];
    int kloc = k0 - base;

    __syncthreads();
    {
      const float4* ws = (const float4*)(W + (long)k0 * 64);
      float4* wd = (float4*)wl;
      wd[t] = ws[t];
      wd[t + 256] = ws[t + 256];
    }
    {
      int r = t >> 3, kq = (t & 7) * 4;
      long rr = row0 + r; if (rr >= M) rr = M - 1;
      float4 v = *(const float4*)(Xp + rr * stride + kloc + kq);
      *(float4*)(xl + r * KCP + kq) = v;
    }
    __syncthreads();

    for (int kg = 0; kg < KC; kg += 4) {
      float4 w0 = *(const float4*)(wl + (kg + 0) * 64 + c0);
      float4 w1 = *(const float4*)(wl + (kg + 1) * 64 + c0);
      float4 w2 = *(const float4*)(wl + (kg + 2) * 64 + c0);
      float4 w3 = *(const float4*)(wl + (kg + 3) * 64 + c0);
#pragma unroll
      for (int r = 0; r < 2; ++r) {
        float4 xv = *(const float4*)(xl + (rg * 2 + r) * KCP + kg);
        acc[r][0] = fmaf(xv.x, w0.x, acc[r][0]);
        acc[r][1] = fmaf(xv.x, w0.y, acc[r][1]);
        acc[r][2] = fmaf(xv.x, w0.z, acc[r][2]);
        acc[r][3] = fmaf(xv.x, w0.w, acc[r][3]);
        acc[r][0] = fmaf(xv.y, w1.x, acc[r][0]);
        acc[r][1] = fmaf(xv.y, w1.y, acc[r][1]);
        acc[r][2] = fmaf(xv.y, w1.z, acc[r][2]);
        acc[r][3] = fmaf(xv.y, w1.w, acc[r][3]);
        acc[r][0] = fmaf(xv.z, w2.x, acc[r][0]);
        acc[r][1] = fmaf(xv.z, w2.y, acc[r][1]);
        acc[r][2] = fmaf(xv.z, w2.z, acc[r][2]);
        acc[r][3] = fmaf(xv.z, w2.w, acc[r][3]);
        acc[r][0] = fmaf(xv.w, w3.x, acc[r][0]);
        acc[r][1] = fmaf(xv.w, w3.y, acc[r][1]);
        acc[r][2] = fmaf(xv.w, w3.z, acc[r][2]);
        acc[r][3] = fmaf(xv.w, w3.w, acc[r][3]);
      }
    }
  }

  float4 bv = make_float4(0.f, 0.f, 0.f, 0.f);
  float4 asv = make_float4(0.f, 0.f, 0.f, 0.f);
  float4 adv = make_float4(0.f, 0.f, 0.f, 0.f);
  if (bias) bv = *(const float4*)(bias + c0);
  if (a_s) asv = *(const float4*)(a_s + c0);
  if (a_d) adv = *(const float4*)(a_d + c0);

#pragma unroll
  for (int r = 0; r < 2; ++r) {
    long m = row0 + rg * 2 + r;
    bool ok = m < M;
    float v0 = acc[r][0] + bv.x, v1 = acc[r][1] + bv.y;
    float v2 = acc[r][2] + bv.z, v3 = acc[r][3] + bv.w;
    if (mode == 1) {
      if (ok)
        *(float4*)(Y + m * 64 + c0) = make_float4(
            fmaxf(v0, 0.f), fmaxf(v1, 0.f), fmaxf(v2, 0.f), fmaxf(v3, 0.f));
    } else if (mode == 2) {
      if (ok) {
        if (c0 < 32) {
          *(float4*)(Y + m * 32 + c0) = make_float4(v0, v1, v2, v3);
        } else {
          float4 o;
          o.x = fmaxf(v0, 0.f) + log1pf(__expf(-fabsf(v0))) + 1e-6f;
          o.y = fmaxf(v1, 0.f) + log1pf(__expf(-fabsf(v1))) + 1e-6f;
          o.z = fmaxf(v2, 0.f) + log1pf(__expf(-fabsf(v2))) + 1e-6f;
          o.w = fmaxf(v3, 0.f) + log1pf(__expf(-fabsf(v3))) + 1e-6f;
          *(float4*)(Y2 + m * 32 + (c0 - 32)) = o;
        }
      }
    } else if (ok && Y) {
      *(float4*)(Y + m * 64 + c0) = make_float4(v0, v1, v2, v3);
    }
    if (a_s) {
      float s = acc[r][0] * asv.x + acc[r][1] * asv.y + acc[r][2] * asv.z + acc[r][3] * asv.w;
      s += __shfl_xor(s, 1); s += __shfl_xor(s, 2);
      s += __shfl_xor(s, 4); s += __shfl_xor(s, 8);
      if (ok && cg == 0) al_s[m] = s;
    }
    if (a_d) {
      float s = acc[r][0] * adv.x + acc[r][1] * adv.y + acc[r][2] * adv.z + acc[r][3] * adv.w;
      s += __shfl_xor(s, 1); s += __shfl_xor(s, 2);
      s += __shfl_xor(s, 4); s += __shfl_xor(s, 8);
      if (ok && cg == 0) al_d[m] = s;
    }
  }
}

// ---------------------------------------------------------------------------
// NOUT=256 projection (tiled, BR=32): X and W staged in LDS.
// mode: 3 = store bf16 (used for all H=4 hs tables)
// ---------------------------------------------------------------------------
__global__ __launch_bounds__(256) void proj_kernel(
    XSrc xsrc, int M, int K,
    const float* __restrict__ W, const float* __restrict__ bias, int mode,
    const float* __restrict__ a_s, const float* __restrict__ a_d,
    float* __restrict__ al_s, float* __restrict__ al_d,
    float* __restrict__ Y, float* __restrict__ Y2) {
  constexpr int NOUT = 256;
  constexpr int KC = 32;
  constexpr int RPT = 8;
  constexpr int BR = 32;
  constexpr int KCP = 36;
  constexpr int H = 4;
  __shared__ float wl[KC * NOUT];
  __shared__ float xl[BR * KCP];

  int t = threadIdx.x;
  int cg = t & 63, rg = t >> 6;
  int c0 = cg * 4;
  long row0 = (long)blockIdx.x * BR;

  float acc[RPT][4];
#pragma unroll
  for (int r = 0; r < RPT; ++r)
#pragma unroll
    for (int j = 0; j < 4; ++j) acc[r][j] = 0.f;

  for (int k0 = 0; k0 < K; k0 += KC) {
    int kc = min(KC, K - k0);
    int seg = 0; int base = 0;
    while (k0 >= base + xsrc.w[seg]) { base += xsrc.w[seg]; ++seg; }
    const float* Xp = xsrc.p[seg];
    int stride = xsrc.w[seg];
    int kloc = k0 - base;

    __syncthreads();
    {
      const float4* wsrc = (const float4*)(W + (long)k0 * NOUT);
      float4* wdst = (float4*)wl;
      for (int i = t; i < (kc * NOUT) >> 2; i += 256) wdst[i] = wsrc[i];
    }
    for (int i = t; i < BR * 8; i += 256) {
      int r = i >> 3, kq = (i & 7) * 4;
      if (kq < kc) {
        long rr = row0 + r; if (rr >= M) rr = M - 1;
        float4 v = *(const float4*)(Xp + rr * stride + kloc + kq);
        *(float4*)(xl + r * KCP + kq) = v;
      }
    }
    __syncthreads();

    for (int kg = 0; kg < kc; kg += 4) {
      float4 w0 = *(const float4*)(wl + (kg + 0) * NOUT + c0);
      float4 w1 = *(const float4*)(wl + (kg + 1) * NOUT + c0);
      float4 w2 = *(const float4*)(wl + (kg + 2) * NOUT + c0);
      float4 w3 = *(const float4*)(wl + (kg + 3) * NOUT + c0);
      float4 xv[RPT];
#pragma unroll
      for (int r = 0; r < RPT; ++r)
        xv[r] = *(const float4*)(xl + (rg * RPT + r) * KCP + kg);
#pragma unroll
      for (int r = 0; r < RPT; ++r) {
        acc[r][0] = fmaf(xv[r].x, w0.x, acc[r][0]);
        acc[r][1] = fmaf(xv[r].x, w0.y, acc[r][1]);
        acc[r][2] = fmaf(xv[r].x, w0.z, acc[r][2]);
        acc[r][3] = fmaf(xv[r].x, w0.w, acc[r][3]);
        acc[r][0] = fmaf(xv[r].y, w1.x, acc[r][0]);
        acc[r][1] = fmaf(xv[r].y, w1.y, acc[r][1]);
        acc[r][2] = fmaf(xv[r].y, w1.z, acc[r][2]);
        acc[r][3] = fmaf(xv[r].y, w1.w, acc[r][3]);
        acc[r][0] = fmaf(xv[r].z, w2.x, acc[r][0]);
        acc[r][1] = fmaf(xv[r].z, w2.y, acc[r][1]);
        acc[r][2] = fmaf(xv[r].z, w2.z, acc[r][2]);
        acc[r][3] = fmaf(xv[r].z, w2.w, acc[r][3]);
        acc[r][0] = fmaf(xv[r].w, w3.x, acc[r][0]);
        acc[r][1] = fmaf(xv[r].w, w3.y, acc[r][1]);
        acc[r][2] = fmaf(xv[r].w, w3.z, acc[r][2]);
        acc[r][3] = fmaf(xv[r].w, w3.w, acc[r][3]);
      }
    }
  }

  float4 asv = make_float4(0.f, 0.f, 0.f, 0.f);
  float4 adv = make_float4(0.f, 0.f, 0.f, 0.f);
  if (a_s) asv = *(const float4*)(a_s + c0);
  if (a_d) adv = *(const float4*)(a_d + c0);

#pragma unroll
  for (int r = 0; r < RPT; ++r) {
    long m = row0 + (long)rg * RPT + r;
    bool ok = m < M;
    if (ok && mode == 3) {
      ushort4 o;
      o.x = f2bf(acc[r][0]); o.y = f2bf(acc[r][1]);
      o.z = f2bf(acc[r][2]); o.w = f2bf(acc[r][3]);
      *(ushort4*)((unsigned short*)Y + m * NOUT + c0) = o;
    }
    if (a_s) {
      float s = acc[r][0] * asv.x + acc[r][1] * asv.y + acc[r][2] * asv.z + acc[r][3] * asv.w;
      s += __shfl_xor(s, 1); s += __shfl_xor(s, 2);
      s += __shfl_xor(s, 4); s += __shfl_xor(s, 8);
      if (ok && (cg & 15) == 0) al_s[m * H + (c0 >> 6)] = s;
    }
    if (a_d) {
      float s = acc[r][0] * adv.x + acc[r][1] * adv.y + acc[r][2] * adv.z + acc[r][3] * adv.w;
      s += __shfl_xor(s, 1); s += __shfl_xor(s, 2);
      s += __shfl_xor(s, 4); s += __shfl_xor(s, 8);
      if (ok && (cg & 15) == 0) al_d[m * H + (c0 >> 6)] = s;
    }
  }
  (void)bias; (void)Y2;
}

// ---------------------------------------------------------------------------
// Fused GAT layer, H=4 C=64, bf16 hs: one wave per node covers all heads.
// Per-lane online softmax (h = lane>>4), 2 independent states for ILP,
// self-loop as initial state.  Epilogue: head-mean + bias + relu.
// ---------------------------------------------------------------------------
__device__ __forceinline__ void fma4_bf(float4& a, float al, ushort4 u) {
  a.x = fmaf(al, bf2f(u.x), a.x); a.y = fmaf(al, bf2f(u.y), a.y);
  a.z = fmaf(al, bf2f(u.z), a.z); a.w = fmaf(al, bf2f(u.w), a.w);
}
__device__ __forceinline__ void scale4(float4& a, float s) {
  a.x *= s; a.y *= s; a.z *= s; a.w *= s;
}

template <bool SELFLOOP>
__global__ __launch_bounds__(256) void gat4_fused(
    int Nd, const int* __restrict__ dptr, const int* __restrict__ csr_src,
    const float* __restrict__ csr_ea, const float* __restrict__ al_s,
    const float* __restrict__ al_d, const float* __restrict__ dote,
    const float* __restrict__ loop_ea, const unsigned short* __restrict__ hs,
    const float* __restrict__ bias, float* __restrict__ out) {
  int wave = threadIdx.x >> 6, lane = threadIdx.x & 63;
  int n = blockIdx.x * 4 + wave;
  if (n >= Nd) return;
  int h = lane >> 4;
  float ald = al_d[(long)n * 4 + h];
  float de = dote[h];
  int e0 = dptr[n], e1 = dptr[n + 1];
  float m0 = -INFINITY, d0 = 0.f;
  float4 a0 = make_float4(0.f, 0.f, 0.f, 0.f);
  if (SELFLOOP) {
    float l = al_s[(long)n * 4 + h] + ald + loop_ea[n] * de;
    l = (l > 0.f) ? l : 0.2f * l;
    m0 = l; d0 = 1.f;
    ushort4 u = *(const ushort4*)(hs + (long)n * 256 + lane * 4);
    a0.x = bf2f(u.x); a0.y = bf2f(u.y); a0.z = bf2f(u.z); a0.w = bf2f(u.w);
  }
  float m1 = -INFINITY, d1 = 0.f;
  float4 a1 = make_float4(0.f, 0.f, 0.f, 0.f);
  int e = e0;
  for (; e + 2 <= e1; e += 2) {
    int s0 = csr_src[e], s1 = csr_src[e + 1];
    float l0 = al_s[(long)s0 * 4 + h] + ald + csr_ea[e] * de;
    float l1 = al_s[(long)s1 * 4 + h] + ald + csr_ea[e + 1] * de;
    l0 = (l0 > 0.f) ? l0 : 0.2f * l0;
    l1 = (l1 > 0.f) ? l1 : 0.2f * l1;
    ushort4 u0 = *(const ushort4*)(hs + (long)s0 * 256 + lane * 4);
    ushort4 u1 = *(const ushort4*)(hs + (long)s1 * 256 + lane * 4);
    if (l0 > m0) { float sc = __expf(m0 - l0); d0 *= sc; scale4(a0, sc); m0 = l0; }
    float ex0 = __expf(l0 - m0);
    d0 += ex0;
    fma4_bf(a0, ex0, u0);
    if (l1 > m1) { float sc = __expf(m1 - l1); d1 *= sc; scale4(a1, sc); m1 = l1; }
    float ex1 = __expf(l1 - m1);
    d1 += ex1;
    fma4_bf(a1, ex1, u1);
  }
  if (e < e1) {
    int s0 = csr_src[e];
    float l0 = al_s[(long)s0 * 4 + h] + ald + csr_ea[e] * de;
    l0 = (l0 > 0.f) ? l0 : 0.2f * l0;
    ushort4 u0 = *(const ushort4*)(hs + (long)s0 * 256 + lane * 4);
    if (l0 > m0) { float sc = __expf(m0 - l0); d0 *= sc; scale4(a0, sc); m0 = l0; }
    float ex0 = __expf(l0 - m0);
    d0 += ex0;
    fma4_bf(a0, ex0, u0);
  }
  if (m1 != -INFINITY) {
    float M = fmaxf(m0, m1);
    float sA = (m0 == -INFINITY) ? 0.f : __expf(m0 - M);
    float sB = __expf(m1 - M);
    d0 = d0 * sA + d1 * sB;
    a0.x = a0.x * sA + a1.x * sB; a0.y = a0.y * sA + a1.y * sB;
    a0.z = a0.z * sA + a1.z * sB; a0.w = a0.w * sA + a1.w * sB;
  }
  float inv = 1.f / (d0 + 1e-16f);
  scale4(a0, inv);
  a0.x += __shfl_xor(a0.x, 16); a0.y += __shfl_xor(a0.y, 16);
  a0.z += __shfl_xor(a0.z, 16); a0.w += __shfl_xor(a0.w, 16);
  a0.x += __shfl_xor(a0.x, 32); a0.y += __shfl_xor(a0.y, 32);
  a0.z += __shfl_xor(a0.z, 32); a0.w += __shfl_xor(a0.w, 32);
  if (lane < 16) {
    float4 b = *(const float4*)(bias + lane * 4);
    float4 o;
    o.x = fmaxf(a0.x * 0.25f + b.x, 0.f);
    o.y = fmaxf(a0.y * 0.25f + b.y, 0.f);
    o.z = fmaxf(a0.z * 0.25f + b.z, 0.f);
    o.w = fmaxf(a0.w * 0.25f + b.w, 0.f);
    *(float4*)(out + (long)n * 64 + lane * 4) = o;
  }
}

// Fused GAT layer, H=1 C=64, fp32 hs (bipartite): wave per node, lane=channel.
__global__ __launch_bounds__(256) void gat1_fused(
    int Nd, const int* __restrict__ dptr, const int* __restrict__ csr_src,
    const float* __restrict__ csr_ea, const float* __restrict__ al_s,
    const float* __restrict__ al_d, const float* __restrict__ dote,
    const float* __restrict__ hs, const float* __restrict__ bias,
    float* __restrict__ out) {
  int wave = threadIdx.x >> 6, lane = threadIdx.x & 63;
  int n = blockIdx.x * 4 + wave;
  if (n >= Nd) return;
  float ald = al_d[n];
  float de = dote[0];
  int e0 = dptr[n], e1 = dptr[n + 1];
  float m0 = -INFINITY, d0 = 0.f, acc0 = 0.f;
  float m1 = -INFINITY, d1 = 0.f, acc1 = 0.f;
  int e = e0;
  for (; e + 2 <= e1; e += 2) {
    int s0 = csr_src[e], s1 = csr_src[e + 1];
    float l0 = al_s[s0] + ald + csr_ea[e] * de;
    float l1 = al_s[s1] + ald + csr_ea[e + 1] * de;
    l0 = (l0 > 0.f) ? l0 : 0.2f * l0;
    l1 = (l1 > 0.f) ? l1 : 0.2f * l1;
    float h0 = hs[(long)s0 * 64 + lane];
    float h1 = hs[(long)s1 * 64 + lane];
    if (l0 > m0) { float sc = __expf(m0 - l0); d0 *= sc; acc0 *= sc; m0 = l0; }
    float ex0 = __expf(l0 - m0);
    d0 += ex0; acc0 = fmaf(ex0, h0, acc0);
    if (l1 > m1) { float sc = __expf(m1 - l1); d1 *= sc; acc1 *= sc; m1 = l1; }
    float ex1 = __expf(l1 - m1);
    d1 += ex1; acc1 = fmaf(ex1, h1, acc1);
  }
  if (e < e1) {
    int s0 = csr_src[e];
    float l0 = al_s[s0] + ald + csr_ea[e] * de;
    l0 = (l0 > 0.f) ? l0 : 0.2f * l0;
    float h0 = hs[(long)s0 * 64 + lane];
    if (l0 > m0) { float sc = __expf(m0 - l0); d0 *= sc; acc0 *= sc; m0 = l0; }
    float ex0 = __expf(l0 - m0);
    d0 += ex0; acc0 = fmaf(ex0, h0, acc0);
  }
  if (m1 != -INFINITY) {
    float M = fmaxf(m0, m1);
    float sA = (m0 == -INFINITY) ? 0.f : __expf(m0 - M);
    float sB = __expf(m1 - M);
    d0 = d0 * sA + d1 * sB;
    acc0 = acc0 * sA + acc1 * sB;
  }
  float o = acc0 / (d0 + 1e-16f);
  out[(long)n * 64 + lane] = fmaxf(o + bias[lane], 0.f);
}

// ---------------------------------------------------------------------------
extern "C" void kernel_launch(void* const* d_in, const int* in_sizes, int n_in,
                              void* d_out, int out_size, void* d_ws, size_t ws_size,
                              hipStream_t stream) {
  const float* sp_mean = (const float*)d_in[0];
  const float* sp_std  = (const float*)d_in[1];
  const void*  nanmask = d_in[2];
  const float* sp_gen  = (const float*)d_in[3];
  const float* sp_phy  = (const float*)d_in[4];
  const float* spat_x  = (const float*)d_in[5];
  const float* spat_g  = (const float*)d_in[6];
  const int*   ss_ei   = (const int*)d_in[7];
  const float* ss_ea   = (const float*)d_in[8];
  const int*   bip_ei  = (const int*)d_in[9];
  const float* bip_ea  = (const float*)d_in[10];
  const int*   sp_ei   = (const int*)d_in[11];
  const float* sp_ea   = (const float*)d_in[12];
  const float* sg0_W = (const float*)d_in[13]; const float* sg0_as = (const float*)d_in[14];
  const float* sg0_ad = (const float*)d_in[15]; const float* sg0_ae = (const float*)d_in[16];
  const float* sg0_We = (const float*)d_in[17]; const float* sg0_b = (const float*)d_in[18];
  const float* sg1_W = (const float*)d_in[19]; const float* sg1_as = (const float*)d_in[20];
  const float* sg1_ad = (const float*)d_in[21]; const float* sg1_ae = (const float*)d_in[22];
  const float* sg1_We = (const float*)d_in[23]; const float* sg1_b = (const float*)d_in[24];
  const float* pg0_W = (const float*)d_in[25]; const float* pg0_as = (const float*)d_in[26];
  const float* pg0_ad = (const float*)d_in[27]; const float* pg0_ae = (const float*)d_in[28];
  const float* pg0_We = (const float*)d_in[29]; const float* pg0_b = (const float*)d_in[30];
  const float* pg1_W = (const float*)d_in[31]; const float* pg1_as = (const float*)d_in[32];
  const float* pg1_ad = (const float*)d_in[33]; const float* pg1_ae = (const float*)d_in[34];
  const float* pg1_We = (const float*)d_in[35]; const float* pg1_b = (const float*)d_in[36];
  const float* bp_Ws = (const float*)d_in[37]; const float* bp_Wd = (const float*)d_in[38];
  const float* bp_as = (const float*)d_in[39]; const float* bp_ad = (const float*)d_in[40];
  const float* bp_ae = (const float*)d_in[41]; const float* bp_We = (const float*)d_in[42];
  const float* bp_b  = (const float*)d_in[43];
  const float* sl_W  = (const float*)d_in[44]; const float* sl_b  = (const float*)d_in[45];
  const float* fc_W  = (const float*)d_in[46]; const float* fc_b  = (const float*)d_in[47];

  // ---- workspace layout ----
  char* wsb = (char*)d_ws;
  size_t off = 0;
  auto A = [&](size_t nbytes) -> void* {
    void* p = wsb + off;
    off += (nbytes + 255) & ~(size_t)255;
    return p;
  };
  // --- zeroed region (single memset): partitioned counters ---
  int* ss_cp = (int*)A((size_t)8 * NSPAT * 4);
  int* bp_cp = (int*)A((size_t)8 * NSP * 4);
  int* pp_cp = (int*)A((size_t)8 * NSP * 4);
  size_t zbytes = off;
  // --- rest ---
  int*   flag  = (int*)A(4);
  float* dotes = (float*)A(5 * 4 * sizeof(float));
  float* alS   = (float*)A((size_t)NSP * 4 * 4);
  float* alD   = (float*)A((size_t)NSP * 4 * 4);
  float* spc96 = (float*)A((size_t)NSP * 96 * 4);
  float* sp_in = (float*)A((size_t)NSP * 64 * 4);
  float* h0    = (float*)A((size_t)NSPAT * 16 * 4);
  float* h_a   = (float*)A((size_t)NSPAT * 64 * 4);
  float* h_b   = (float*)A((size_t)NSPAT * 64 * 4);
  float* HS    = (float*)A((size_t)NSP * 256 * 4);   // bf16 hs rows
  float* sts   = (float*)A((size_t)NSP * 64 * 4);
  float* x1    = (float*)A((size_t)NSP * 64 * 4);
  int*   ss_ptr = (int*)A((NSPAT + 1) * 4);
  int*   ss_src = (int*)A((size_t)ESS * 4);
  float* ss_cea = (float*)A((size_t)ESS * 4);
  int*   ss_rnk = (int*)A((size_t)ESS * 4);
  float* ss_lea = (float*)A((size_t)NSPAT * 4);
  int*   bp_ptr = (int*)A((NSP + 1) * 4);
  int*   bp_src = (int*)A((size_t)EBIP * 4);
  float* bp_cea = (float*)A((size_t)EBIP * 4);
  int*   bp_rnk = (int*)A((size_t)EBIP * 4);
  int*   pp_ptr = (int*)A((NSP + 1) * 4);
  int*   pp_src = (int*)A((size_t)ESP * 4);
  float* pp_cea = (float*)A((size_t)ESP * 4);
  int*   pp_rnk = (int*)A((size_t)ESP * 4);
  float* pp_lea = (float*)A((size_t)NSP * 4);
  (void)ws_size; (void)in_sizes; (void)n_in; (void)out_size;

  const int TB = 256;
  hipMemsetAsync(wsb, 0, zbytes, stream);

  // ---- graph builds: partitioned count -> scan(+merge) -> scatter ----
  count3_kernel<<<cdiv_host(ESS + EBIP + ESP, TB), TB, 0, stream>>>(
      ss_ei + ESS, ESS, ss_cp, ss_rnk, NSPAT,
      bip_ei + EBIP, EBIP, bp_cp, bp_rnk, NSP,
      sp_ei + ESP, ESP, pp_cp, pp_rnk, NSP);
  scan3_kernel<<<3, 1024, 0, stream>>>(ss_cp, NSPAT, ss_ptr, bp_cp, NSP, bp_ptr, pp_cp, NSP, pp_ptr);
  scatter3_kernel<<<cdiv_host(ESS + EBIP + ESP, TB), TB, 0, stream>>>(
      ss_ei, ss_ei + ESS, ss_ea, ESS, ss_ptr, ss_cp, ss_rnk, NSPAT, ss_src, ss_cea,
      bip_ei, bip_ei + EBIP, bip_ea, EBIP, bp_ptr, bp_cp, bp_rnk, NSP, bp_src, bp_cea,
      sp_ei, sp_ei + ESP, sp_ea, ESP, pp_ptr, pp_cp, pp_rnk, NSP, pp_src, pp_cea);
  leafin_csr2<<<cdiv_host(NSPAT + NSP, TB), TB, 0, stream>>>(
      ss_ptr, ss_cea, NSPAT, ss_lea, pp_ptr, pp_cea, NSP, pp_lea);

  dote_all_kernel<<<6, 256, 0, stream>>>(sg0_We, sg0_ae, sg1_We, sg1_ae, bp_We, bp_ae,
                                         pg0_We, pg0_ae, pg1_We, pg1_ae,
                                         (const unsigned int*)nanmask, dotes, flag);

  // ---- prep: spc96 + h0 in one launch ----
  build_pre_kernel<<<cdiv_host((long)NSP * 96 + (long)NSPAT * 16, TB), TB, 0, stream>>>(
      sp_mean, sp_std, nanmask, flag, spat_x, spat_g, spc96, h0);

  // ---- species input MLP ----
  {
    XSrc xs{}; xs.p[0] = spc96; xs.w[0] = 96; xs.p[1] = sp_gen; xs.w[1] = 64;
    xs.p[2] = sp_phy; xs.w[2] = 128; xs.n = 3;
    proj64_kernel<<<cdiv_host(NSP, 32), TB, 0, stream>>>(xs, NSP, 288, sl_W, sl_b, 1,
        nullptr, nullptr, nullptr, nullptr, sp_in, nullptr);
  }

  // ---- spatial GNN ----
  {
    XSrc xs{}; xs.p[0] = h0; xs.w[0] = 16; xs.n = 1;
    proj_kernel<<<cdiv_host(NSPAT, 32), TB, 0, stream>>>(xs, NSPAT, 16, sg0_W, nullptr, 3,
        sg0_as, sg0_ad, alS, alD, HS, nullptr);
  }
  gat4_fused<true><<<cdiv_host(NSPAT, 4), TB, 0, stream>>>(
      NSPAT, ss_ptr, ss_src, ss_cea, alS, alD, dotes + 0, ss_lea,
      (const unsigned short*)HS, sg0_b, h_a);
  {
    XSrc xs{}; xs.p[0] = h_a; xs.w[0] = 64; xs.n = 1;
    proj_kernel<<<cdiv_host(NSPAT, 32), TB, 0, stream>>>(xs, NSPAT, 64, sg1_W, nullptr, 3,
        sg1_as, sg1_ad, alS, alD, HS, nullptr);
  }
  gat4_fused<true><<<cdiv_host(NSPAT, 4), TB, 0, stream>>>(
      NSPAT, ss_ptr, ss_src, ss_cea, alS, alD, dotes + 4, ss_lea,
      (const unsigned short*)HS, sg1_b, h_b);

  // ---- bipartite GAT (spatial -> species), H=1, concat ----
  {
    XSrc xs{}; xs.p[0] = h_b; xs.w[0] = 64; xs.n = 1;
    proj64_kernel<<<cdiv_host(NSPAT, 32), TB, 0, stream>>>(xs, NSPAT, 64, bp_Ws, nullptr, 0,
        bp_as, nullptr, alS, nullptr, h_a, nullptr);   // h_a := hs_src (fp32)
  }
  {
    XSrc xs{}; xs.p[0] = sp_gen; xs.w[0] = 64; xs.p[1] = sp_phy; xs.w[1] = 128; xs.n = 2;
    proj64_kernel<<<cdiv_host(NSP, 32), TB, 0, stream>>>(xs, NSP, 192, bp_Wd, nullptr, 0,
        nullptr, bp_ad, nullptr, alD, nullptr, nullptr);   // only al_d needed
  }
  gat1_fused<<<cdiv_host(NSP, 4), TB, 0, stream>>>(
      NSP, bp_ptr, bp_src, bp_cea, alS, alD, dotes + 8, h_a, bp_b, sts);

  // ---- species GNN ----
  {
    XSrc xs{}; xs.p[0] = sts; xs.w[0] = 64; xs.p[1] = sp_in; xs.w[1] = 64; xs.n = 2;
    proj_kernel<<<cdiv_host(NSP, 32), TB, 0, stream>>>(xs, NSP, 128, pg0_W, nullptr, 3,
        pg0_as, pg0_ad, alS, alD, HS, nullptr);
  }
  gat4_fused<true><<<cdiv_host(NSP, 4), TB, 0, stream>>>(
      NSP, pp_ptr, pp_src, pp_cea, alS, alD, dotes + 12, pp_lea,
      (const unsigned short*)HS, pg0_b, x1);
  {
    XSrc xs{}; xs.p[0] = x1; xs.w[0] = 64; xs.n = 1;
    proj_kernel<<<cdiv_host(NSP, 32), TB, 0, stream>>>(xs, NSP, 64, pg1_W, nullptr, 3,
        pg1_as, pg1_ad, alS, alD, HS, nullptr);
  }
  gat4_fused<true><<<cdiv_host(NSP, 4), TB, 0, stream>>>(
      NSP, pp_ptr, pp_src, pp_cea, alS, alD, dotes + 16, pp_lea,
      (const unsigned short*)HS, pg1_b, sts);   // sts := x2

  // ---- final linear fused with split/softplus ----
  {
    XSrc xs{}; xs.p[0] = sts; xs.w[0] = 64; xs.n = 1;
    proj64_kernel<<<cdiv_host(NSP, 32), TB, 0, stream>>>(xs, NSP, 64, fc_W, fc_b, 2,
        nullptr, nullptr, nullptr, nullptr, (float*)d_out, (float*)d_out + (long)NSP * 32);
  }
}

// Round 11
// 524.884 us; speedup vs baseline: 1.2516x; 1.2516x over previous
//
#include <hip/hip_runtime.h>
#include <hip/hip_bf16.h>

#define NSP   20000
#define NSPAT 10000
#define ESS   160000
#define EBIP  320000
#define ESP   320000

static inline int cdiv_host(long a, long b) { return (int)((a + b - 1) / b); }

__device__ __forceinline__ float wave_red_sum(float p) {
#pragma unroll
  for (int m = 32; m >= 1; m >>= 1) p += __shfl_xor(p, m, 64);
  return p;
}

__device__ __forceinline__ float bf2f(unsigned short u) {
  return __uint_as_float(((unsigned int)u) << 16);
}
__device__ __forceinline__ unsigned short f2bf(float f) {
  unsigned int u = __float_as_uint(f);
  unsigned int r = (u + 0x7FFF + ((u >> 16) & 1)) >> 16;  // RN-even
  return (unsigned short)r;
}

// ---------------------------------------------------------------------------
// combined prep: spc96 = [mean|std|vis] (NSP*96) and h0 = [spat_x|spat_g]
// (NSPAT*16).  Mask mode from *flag (0=int32, 1=bytes, 2=float).
// ---------------------------------------------------------------------------
__global__ void build_pre_kernel(const float* __restrict__ mean, const float* __restrict__ stdv,
                                 const void* __restrict__ mask, const int* __restrict__ flag,
                                 const float* __restrict__ sx, const float* __restrict__ sg,
                                 float* __restrict__ spc96, float* __restrict__ h0) {
  const long totA = (long)NSP * 96;
  const long totB = (long)NSPAT * 16;
  int mode = *flag;
  for (long i = (long)blockIdx.x * blockDim.x + threadIdx.x; i < totA + totB;
       i += (long)gridDim.x * blockDim.x) {
    if (i < totA) {
      int n = (int)(i / 96), c = (int)(i % 96);
      float v;
      if (c < 32) v = mean[(long)n * 32 + c];
      else if (c < 64) v = stdv[(long)n * 32 + (c - 32)];
      else {
        long j = (long)n * 32 + (c - 64);
        int mv;
        if (mode == 0) mv = ((const int*)mask)[j];
        else if (mode == 2) mv = (((const float*)mask)[j] != 0.0f);
        else mv = (int)((const unsigned char*)mask)[j];
        v = mv ? 0.f : 1.f;   // vis = ~mask
      }
      spc96[i] = v;
    } else {
      long k = i - totA;
      int n = (int)(k / 16), c = (int)(k % 16);
      h0[k] = (c < 12) ? sx[(long)n * 12 + c] : sg[(long)n * 4 + (c - 12)];
    }
  }
}

// ---------------------------------------------------------------------------
// CSR build, 8-way partitioned atomics.  Partition p = (combined_i >> 8) & 7.
// ---------------------------------------------------------------------------
__global__ void count3_kernel(
    const int* c1, int E1, int* cp1, int* rnk1, int n1,
    const int* c2, int E2, int* cp2, int* rnk2, int n2,
    const int* c3, int E3, int* cp3, int* rnk3, int n3) {
  int total = E1 + E2 + E3;
  for (int i = blockIdx.x * blockDim.x + threadIdx.x; i < total; i += gridDim.x * blockDim.x) {
    int p = (i >> 8) & 7;
    if (i < E1) {
      int d = c1[i]; rnk1[i] = atomicAdd(&cp1[p * n1 + d], 1);
    } else if (i < E1 + E2) {
      int j = i - E1;
      int d = c2[j]; rnk2[j] = atomicAdd(&cp2[p * n2 + d], 1);
    } else {
      int j = i - E1 - E2;
      int d = c3[j]; rnk3[j] = atomicAdd(&cp3[p * n3 + d], 1);
    }
  }
}

// parallel per-node partition merge: cp[p*n+d] -> per-partition exclusive
// offsets; cnt[d] = node total.  1 thread per node, coalesced per partition.
__global__ void merge3_kernel(int* cp1, int* c1, int n1,
                              int* cp2, int* c2, int n2,
                              int* cp3, int* c3, int n3) {
  int i = blockIdx.x * blockDim.x + threadIdx.x;
  int total = n1 + n2 + n3;
  if (i >= total) return;
  int *cp, *c; int n, d;
  if (i < n1) { cp = cp1; c = c1; n = n1; d = i; }
  else if (i < n1 + n2) { cp = cp2; c = c2; n = n2; d = i - n1; }
  else { cp = cp3; c = c3; n = n3; d = i - n1 - n2; }
  int s = 0;
#pragma unroll
  for (int p = 0; p < 8; ++p) { int t = cp[p * n + d]; cp[p * n + d] = s; s += t; }
  c[d] = s;
}

__global__ __launch_bounds__(1024) void scan3_kernel(
    const int* cntA, int nA, int* ptrA,
    const int* cntB, int nB, int* ptrB,
    const int* cntC, int nC, int* ptrC) {
  const int* cnt; int n; int* ptr;
  if (blockIdx.x == 0) { cnt = cntA; n = nA; ptr = ptrA; }
  else if (blockIdx.x == 1) { cnt = cntB; n = nB; ptr = ptrB; }
  else { cnt = cntC; n = nC; ptr = ptrC; }
  __shared__ int part[1024];
  int t = threadIdx.x;
  int ch = (n + 1023) / 1024;
  int beg = t * ch, end = min(beg + ch, n);
  int s = 0;
  for (int i = beg; i < end; ++i) s += cnt[i];
  part[t] = s;
  __syncthreads();
  for (int off = 1; off < 1024; off <<= 1) {
    int v = (t >= off) ? part[t - off] : 0;
    __syncthreads();
    part[t] += v;
    __syncthreads();
  }
  int run = (t == 0) ? 0 : part[t - 1];
  for (int i = beg; i < end; ++i) { ptr[i] = run; run += cnt[i]; }
  if (t == 1023) ptr[n] = part[1023];
}

__global__ void scatter3_kernel(
    const int* r1, const int* c1, const float* e1, int E1, const int* p1, const int* cp1, const int* k1, int n1, int* s1, float* a1,
    const int* r2, const int* c2, const float* e2, int E2, const int* p2, const int* cp2, const int* k2, int n2, int* s2, float* a2,
    const int* r3, const int* c3, const float* e3, int E3, const int* p3, const int* cp3, const int* k3, int n3, int* s3, float* a3) {
  int total = E1 + E2 + E3;
  for (int i = blockIdx.x * blockDim.x + threadIdx.x; i < total; i += gridDim.x * blockDim.x) {
    int p = (i >> 8) & 7;
    if (i < E1) {
      int d = c1[i];
      int pos = p1[d] + cp1[p * n1 + d] + k1[i];
      s1[pos] = r1[i]; a1[pos] = e1[i];
    } else if (i < E1 + E2) {
      int j = i - E1;
      int d = c2[j];
      int pos = p2[d] + cp2[p * n2 + d] + k2[j];
      s2[pos] = r2[j]; a2[pos] = e2[j];
    } else {
      int j = i - E1 - E2;
      int d = c3[j];
      int pos = p3[d] + cp3[p * n3 + d] + k3[j];
      s3[pos] = r3[j]; a3[pos] = e3[j];
    }
  }
}

// loop_ea = mean of incoming edge_attr, from contiguous CSR cea
__global__ void leafin_csr2(const int* ptrA, const float* ceaA, int nA, float* leaA,
                            const int* ptrB, const float* ceaB, int nB, float* leaB) {
  int i = blockIdx.x * blockDim.x + threadIdx.x;
  if (i >= nA + nB) return;
  const int* ptr; const float* cea; float* lea; int d;
  if (i < nA) { ptr = ptrA; cea = ceaA; lea = leaA; d = i; }
  else { ptr = ptrB; cea = ceaB; lea = leaB; d = i - nA; }
  int e0 = ptr[d], e1 = ptr[d + 1];
  float s = 0.f;
  for (int e = e0; e < e1; ++e) s += cea[e];
  lea[d] = s / (float)max(e1 - e0, 1);
}

// dot_e[h] per layer (blocks 0..4) + mask-format detect (block 5, 64 lanes)
__global__ void dote_all_kernel(const float* __restrict__ We0, const float* __restrict__ ae0,
                                const float* __restrict__ We1, const float* __restrict__ ae1,
                                const float* __restrict__ Web, const float* __restrict__ aeb,
                                const float* __restrict__ We2, const float* __restrict__ ae2,
                                const float* __restrict__ We3, const float* __restrict__ ae3,
                                const unsigned int* __restrict__ mask,
                                float* __restrict__ dotes, int* __restrict__ flag) {
  int b = blockIdx.x, t = threadIdx.x;
  if (b == 5) {
    if (t < 64) {
      unsigned int w0 = mask[t], w1 = mask[t + 64], w2 = mask[t + 128], w3 = mask[t + 192];
      bool ai = (w0 <= 1u) && (w1 <= 1u) && (w2 <= 1u) && (w3 <= 1u);
      auto okf = [](unsigned int w) { return w == 0u || w == 0x3f800000u; };
      bool af = okf(w0) && okf(w1) && okf(w2) && okf(w3);
      unsigned long long bi = __ballot(ai), bf = __ballot(af);
      if (t == 0) *flag = (bi == ~0ull) ? 0 : ((bf == ~0ull) ? 2 : 1);
    }
    return;
  }
  const float *We, *ae;
  int n, off;
  switch (b) {
    case 0: We = We0; ae = ae0; n = 256; off = 0; break;
    case 1: We = We1; ae = ae1; n = 256; off = 4; break;
    case 2: We = Web; ae = aeb; n = 64;  off = 8; break;
    case 3: We = We2; ae = ae2; n = 256; off = 12; break;
    default: We = We3; ae = ae3; n = 256; off = 16; break;
  }
  if (t < n) {
    float p = wave_red_sum(We[t] * ae[t]);
    if ((t & 63) == 0) dotes[off + (t >> 6)] = p;
  }
}

struct XSrc { const float* p[5]; int w[5]; int n; };

// ---------------------------------------------------------------------------
// NOUT=64 projection, tiled: BR=32 rows/block, KC=32.  4 cols x 2 rows per
// thread.  mode: 0 = bias (skip store if Y null), 1 = bias+relu,
// 2 = final split (mean | softplus+eps).  a_s/a_d: H=1 dots.
// ---------------------------------------------------------------------------
__global__ __launch_bounds__(256) void proj64_kernel(
    XSrc xsrc, int M, int K,
    const float* __restrict__ W, const float* __restrict__ bias, int mode,
    const float* __restrict__ a_s, const float* __restrict__ a_d,
    float* __restrict__ al_s, float* __restrict__ al_d,
    float* __restrict__ Y, float* __restrict__ Y2) {
  constexpr int KC = 32;
  constexpr int BR = 32;
  constexpr int KCP = 36;
  __shared__ float wl[KC * 64];
  __shared__ float xl[BR * KCP];

  int t = threadIdx.x;
  int cg = t & 15, rg = t >> 4;
  int c0 = cg * 4;
  long row0 = (long)blockIdx.x * BR;

  float acc[2][4];
#pragma unroll
  for (int r = 0; r < 2; ++r)
#pragma unroll
    for (int j = 0; j < 4; ++j) acc[r][j] = 0.f;

  for (int k0 = 0; k0 < K; k0 += KC) {
    int seg = 0; int base = 0;
    while (k0 >= base + xsrc.w[seg]) { base += xsrc.w[seg]; ++seg; }
    const float* Xp = xsrc.p[seg];
    int stride = xsrc.w[seg];
    int kloc = k0 - base;

    __syncthreads();
    {
      const float4* ws = (const float4*)(W + (long)k0 * 64);
      float4* wd = (float4*)wl;
      wd[t] = ws[t];
      wd[t + 256] = ws[t + 256];
    }
    {
      int r = t >> 3, kq = (t & 7) * 4;
      long rr = row0 + r; if (rr >= M) rr = M - 1;
      float4 v = *(const float4*)(Xp + rr * stride + kloc + kq);
      *(float4*)(xl + r * KCP + kq) = v;
    }
    __syncthreads();

    for (int kg = 0; kg < KC; kg += 4) {
      float4 w0 = *(const float4*)(wl + (kg + 0) * 64 + c0);
      float4 w1 = *(const float4*)(wl + (kg + 1) * 64 + c0);
      float4 w2 = *(const float4*)(wl + (kg + 2) * 64 + c0);
      float4 w3 = *(const float4*)(wl + (kg + 3) * 64 + c0);
#pragma unroll
      for (int r = 0; r < 2; ++r) {
        float4 xv = *(const float4*)(xl + (rg * 2 + r) * KCP + kg);
        acc[r][0] = fmaf(xv.x, w0.x, acc[r][0]);
        acc[r][1] = fmaf(xv.x, w0.y, acc[r][1]);
        acc[r][2] = fmaf(xv.x, w0.z, acc[r][2]);
        acc[r][3] = fmaf(xv.x, w0.w, acc[r][3]);
        acc[r][0] = fmaf(xv.y, w1.x, acc[r][0]);
        acc[r][1] = fmaf(xv.y, w1.y, acc[r][1]);
        acc[r][2] = fmaf(xv.y, w1.z, acc[r][2]);
        acc[r][3] = fmaf(xv.y, w1.w, acc[r][3]);
        acc[r][0] = fmaf(xv.z, w2.x, acc[r][0]);
        acc[r][1] = fmaf(xv.z, w2.y, acc[r][1]);
        acc[r][2] = fmaf(xv.z, w2.z, acc[r][2]);
        acc[r][3] = fmaf(xv.z, w2.w, acc[r][3]);
        acc[r][0] = fmaf(xv.w, w3.x, acc[r][0]);
        acc[r][1] = fmaf(xv.w, w3.y, acc[r][1]);
        acc[r][2] = fmaf(xv.w, w3.z, acc[r][2]);
        acc[r][3] = fmaf(xv.w, w3.w, acc[r][3]);
      }
    }
  }

  float4 bv = make_float4(0.f, 0.f, 0.f, 0.f);
  float4 asv = make_float4(0.f, 0.f, 0.f, 0.f);
  float4 adv = make_float4(0.f, 0.f, 0.f, 0.f);
  if (bias) bv = *(const float4*)(bias + c0);
  if (a_s) asv = *(const float4*)(a_s + c0);
  if (a_d) adv = *(const float4*)(a_d + c0);

#pragma unroll
  for (int r = 0; r < 2; ++r) {
    long m = row0 + rg * 2 + r;
    bool ok = m < M;
    float v0 = acc[r][0] + bv.x, v1 = acc[r][1] + bv.y;
    float v2 = acc[r][2] + bv.z, v3 = acc[r][3] + bv.w;
    if (mode == 1) {
      if (ok)
        *(float4*)(Y + m * 64 + c0) = make_float4(
            fmaxf(v0, 0.f), fmaxf(v1, 0.f), fmaxf(v2, 0.f), fmaxf(v3, 0.f));
    } else if (mode == 2) {
      if (ok) {
        if (c0 < 32) {
          *(float4*)(Y + m * 32 + c0) = make_float4(v0, v1, v2, v3);
        } else {
          float4 o;
          o.x = fmaxf(v0, 0.f) + log1pf(__expf(-fabsf(v0))) + 1e-6f;
          o.y = fmaxf(v1, 0.f) + log1pf(__expf(-fabsf(v1))) + 1e-6f;
          o.z = fmaxf(v2, 0.f) + log1pf(__expf(-fabsf(v2))) + 1e-6f;
          o.w = fmaxf(v3, 0.f) + log1pf(__expf(-fabsf(v3))) + 1e-6f;
          *(float4*)(Y2 + m * 32 + (c0 - 32)) = o;
        }
      }
    } else if (ok && Y) {
      *(float4*)(Y + m * 64 + c0) = make_float4(v0, v1, v2, v3);
    }
    if (a_s) {
      float s = acc[r][0] * asv.x + acc[r][1] * asv.y + acc[r][2] * asv.z + acc[r][3] * asv.w;
      s += __shfl_xor(s, 1); s += __shfl_xor(s, 2);
      s += __shfl_xor(s, 4); s += __shfl_xor(s, 8);
      if (ok && cg == 0) al_s[m] = s;
    }
    if (a_d) {
      float s = acc[r][0] * adv.x + acc[r][1] * adv.y + acc[r][2] * adv.z + acc[r][3] * adv.w;
      s += __shfl_xor(s, 1); s += __shfl_xor(s, 2);
      s += __shfl_xor(s, 4); s += __shfl_xor(s, 8);
      if (ok && cg == 0) al_d[m] = s;
    }
  }
}

// ---------------------------------------------------------------------------
// NOUT=256 projection (tiled, BR=32): X and W staged in LDS.
// mode: 3 = store bf16 (used for all H=4 hs tables)
// ---------------------------------------------------------------------------
__global__ __launch_bounds__(256) void proj_kernel(
    XSrc xsrc, int M, int K,
    const float* __restrict__ W, const float* __restrict__ bias, int mode,
    const float* __restrict__ a_s, const float* __restrict__ a_d,
    float* __restrict__ al_s, float* __restrict__ al_d,
    float* __restrict__ Y, float* __restrict__ Y2) {
  constexpr int NOUT = 256;
  constexpr int KC = 32;
  constexpr int RPT = 8;
  constexpr int BR = 32;
  constexpr int KCP = 36;
  constexpr int H = 4;
  __shared__ float wl[KC * NOUT];
  __shared__ float xl[BR * KCP];

  int t = threadIdx.x;
  int cg = t & 63, rg = t >> 6;
  int c0 = cg * 4;
  long row0 = (long)blockIdx.x * BR;

  float acc[RPT][4];
#pragma unroll
  for (int r = 0; r < RPT; ++r)
#pragma unroll
    for (int j = 0; j < 4; ++j) acc[r][j] = 0.f;

  for (int k0 = 0; k0 < K; k0 += KC) {
    int kc = min(KC, K - k0);
    int seg = 0; int base = 0;
    while (k0 >= base + xsrc.w[seg]) { base += xsrc.w[seg]; ++seg; }
    const float* Xp = xsrc.p[seg];
    int stride = xsrc.w[seg];
    int kloc = k0 - base;

    __syncthreads();
    {
      const float4* wsrc = (const float4*)(W + (long)k0 * NOUT);
      float4* wdst = (float4*)wl;
      for (int i = t; i < (kc * NOUT) >> 2; i += 256) wdst[i] = wsrc[i];
    }
    for (int i = t; i < BR * 8; i += 256) {
      int r = i >> 3, kq = (i & 7) * 4;
      if (kq < kc) {
        long rr = row0 + r; if (rr >= M) rr = M - 1;
        float4 v = *(const float4*)(Xp + rr * stride + kloc + kq);
        *(float4*)(xl + r * KCP + kq) = v;
      }
    }
    __syncthreads();

    for (int kg = 0; kg < kc; kg += 4) {
      float4 w0 = *(const float4*)(wl + (kg + 0) * NOUT + c0);
      float4 w1 = *(const float4*)(wl + (kg + 1) * NOUT + c0);
      float4 w2 = *(const float4*)(wl + (kg + 2) * NOUT + c0);
      float4 w3 = *(const float4*)(wl + (kg + 3) * NOUT + c0);
      float4 xv[RPT];
#pragma unroll
      for (int r = 0; r < RPT; ++r)
        xv[r] = *(const float4*)(xl + (rg * RPT + r) * KCP + kg);
#pragma unroll
      for (int r = 0; r < RPT; ++r) {
        acc[r][0] = fmaf(xv[r].x, w0.x, acc[r][0]);
        acc[r][1] = fmaf(xv[r].x, w0.y, acc[r][1]);
        acc[r][2] = fmaf(xv[r].x, w0.z, acc[r][2]);
        acc[r][3] = fmaf(xv[r].x, w0.w, acc[r][3]);
        acc[r][0] = fmaf(xv[r].y, w1.x, acc[r][0]);
        acc[r][1] = fmaf(xv[r].y, w1.y, acc[r][1]);
        acc[r][2] = fmaf(xv[r].y, w1.z, acc[r][2]);
        acc[r][3] = fmaf(xv[r].y, w1.w, acc[r][3]);
        acc[r][0] = fmaf(xv[r].z, w2.x, acc[r][0]);
        acc[r][1] = fmaf(xv[r].z, w2.y, acc[r][1]);
        acc[r][2] = fmaf(xv[r].z, w2.z, acc[r][2]);
        acc[r][3] = fmaf(xv[r].z, w2.w, acc[r][3]);
        acc[r][0] = fmaf(xv[r].w, w3.x, acc[r][0]);
        acc[r][1] = fmaf(xv[r].w, w3.y, acc[r][1]);
        acc[r][2] = fmaf(xv[r].w, w3.z, acc[r][2]);
        acc[r][3] = fmaf(xv[r].w, w3.w, acc[r][3]);
      }
    }
  }

  float4 asv = make_float4(0.f, 0.f, 0.f, 0.f);
  float4 adv = make_float4(0.f, 0.f, 0.f, 0.f);
  if (a_s) asv = *(const float4*)(a_s + c0);
  if (a_d) adv = *(const float4*)(a_d + c0);

#pragma unroll
  for (int r = 0; r < RPT; ++r) {
    long m = row0 + (long)rg * RPT + r;
    bool ok = m < M;
    if (ok && mode == 3) {
      ushort4 o;
      o.x = f2bf(acc[r][0]); o.y = f2bf(acc[r][1]);
      o.z = f2bf(acc[r][2]); o.w = f2bf(acc[r][3]);
      *(ushort4*)((unsigned short*)Y + m * NOUT + c0) = o;
    }
    if (a_s) {
      float s = acc[r][0] * asv.x + acc[r][1] * asv.y + acc[r][2] * asv.z + acc[r][3] * asv.w;
      s += __shfl_xor(s, 1); s += __shfl_xor(s, 2);
      s += __shfl_xor(s, 4); s += __shfl_xor(s, 8);
      if (ok && (cg & 15) == 0) al_s[m * H + (c0 >> 6)] = s;
    }
    if (a_d) {
      float s = acc[r][0] * adv.x + acc[r][1] * adv.y + acc[r][2] * adv.z + acc[r][3] * adv.w;
      s += __shfl_xor(s, 1); s += __shfl_xor(s, 2);
      s += __shfl_xor(s, 4); s += __shfl_xor(s, 8);
      if (ok && (cg & 15) == 0) al_d[m * H + (c0 >> 6)] = s;
    }
  }
  (void)bias; (void)Y2;
}

// ---------------------------------------------------------------------------
// Fused GAT layer, H=4 C=64, bf16 hs: one wave per node covers all heads.
// Per-lane online softmax (h = lane>>4), 2 independent states for ILP,
// self-loop as initial state.  Epilogue: head-mean + bias + relu.
// ---------------------------------------------------------------------------
__device__ __forceinline__ void fma4_bf(float4& a, float al, ushort4 u) {
  a.x = fmaf(al, bf2f(u.x), a.x); a.y = fmaf(al, bf2f(u.y), a.y);
  a.z = fmaf(al, bf2f(u.z), a.z); a.w = fmaf(al, bf2f(u.w), a.w);
}
__device__ __forceinline__ void scale4(float4& a, float s) {
  a.x *= s; a.y *= s; a.z *= s; a.w *= s;
}

template <bool SELFLOOP>
__global__ __launch_bounds__(256) void gat4_fused(
    int Nd, const int* __restrict__ dptr, const int* __restrict__ csr_src,
    const float* __restrict__ csr_ea, const float* __restrict__ al_s,
    const float* __restrict__ al_d, const float* __restrict__ dote,
    const float* __restrict__ loop_ea, const unsigned short* __restrict__ hs,
    const float* __restrict__ bias, float* __restrict__ out) {
  int wave = threadIdx.x >> 6, lane = threadIdx.x & 63;
  int n = blockIdx.x * 4 + wave;
  if (n >= Nd) return;
  int h = lane >> 4;
  float ald = al_d[(long)n * 4 + h];
  float de = dote[h];
  int e0 = dptr[n], e1 = dptr[n + 1];
  float m0 = -INFINITY, d0 = 0.f;
  float4 a0 = make_float4(0.f, 0.f, 0.f, 0.f);
  if (SELFLOOP) {
    float l = al_s[(long)n * 4 + h] + ald + loop_ea[n] * de;
    l = (l > 0.f) ? l : 0.2f * l;
    m0 = l; d0 = 1.f;
    ushort4 u = *(const ushort4*)(hs + (long)n * 256 + lane * 4);
    a0.x = bf2f(u.x); a0.y = bf2f(u.y); a0.z = bf2f(u.z); a0.w = bf2f(u.w);
  }
  float m1 = -INFINITY, d1 = 0.f;
  float4 a1 = make_float4(0.f, 0.f, 0.f, 0.f);
  int e = e0;
  for (; e + 2 <= e1; e += 2) {
    int s0 = csr_src[e], s1 = csr_src[e + 1];
    float l0 = al_s[(long)s0 * 4 + h] + ald + csr_ea[e] * de;
    float l1 = al_s[(long)s1 * 4 + h] + ald + csr_ea[e + 1] * de;
    l0 = (l0 > 0.f) ? l0 : 0.2f * l0;
    l1 = (l1 > 0.f) ? l1 : 0.2f * l1;
    ushort4 u0 = *(const ushort4*)(hs + (long)s0 * 256 + lane * 4);
    ushort4 u1 = *(const ushort4*)(hs + (long)s1 * 256 + lane * 4);
    if (l0 > m0) { float sc = __expf(m0 - l0); d0 *= sc; scale4(a0, sc); m0 = l0; }
    float ex0 = __expf(l0 - m0);
    d0 += ex0;
    fma4_bf(a0, ex0, u0);
    if (l1 > m1) { float sc = __expf(m1 - l1); d1 *= sc; scale4(a1, sc); m1 = l1; }
    float ex1 = __expf(l1 - m1);
    d1 += ex1;
    fma4_bf(a1, ex1, u1);
  }
  if (e < e1) {
    int s0 = csr_src[e];
    float l0 = al_s[(long)s0 * 4 + h] + ald + csr_ea[e] * de;
    l0 = (l0 > 0.f) ? l0 : 0.2f * l0;
    ushort4 u0 = *(const ushort4*)(hs + (long)s0 * 256 + lane * 4);
    if (l0 > m0) { float sc = __expf(m0 - l0); d0 *= sc; scale4(a0, sc); m0 = l0; }
    float ex0 = __expf(l0 - m0);
    d0 += ex0;
    fma4_bf(a0, ex0, u0);
  }
  if (m1 != -INFINITY) {
    float M = fmaxf(m0, m1);
    float sA = (m0 == -INFINITY) ? 0.f : __expf(m0 - M);
    float sB = __expf(m1 - M);
    d0 = d0 * sA + d1 * sB;
    a0.x = a0.x * sA + a1.x * sB; a0.y = a0.y * sA + a1.y * sB;
    a0.z = a0.z * sA + a1.z * sB; a0.w = a0.w * sA + a1.w * sB;
  }
  float inv = 1.f / (d0 + 1e-16f);
  scale4(a0, inv);
  a0.x += __shfl_xor(a0.x, 16); a0.y += __shfl_xor(a0.y, 16);
  a0.z += __shfl_xor(a0.z, 16); a0.w += __shfl_xor(a0.w, 16);
  a0.x += __shfl_xor(a0.x, 32); a0.y += __shfl_xor(a0.y, 32);
  a0.z += __shfl_xor(a0.z, 32); a0.w += __shfl_xor(a0.w, 32);
  if (lane < 16) {
    float4 b = *(const float4*)(bias + lane * 4);
    float4 o;
    o.x = fmaxf(a0.x * 0.25f + b.x, 0.f);
    o.y = fmaxf(a0.y * 0.25f + b.y, 0.f);
    o.z = fmaxf(a0.z * 0.25f + b.z, 0.f);
    o.w = fmaxf(a0.w * 0.25f + b.w, 0.f);
    *(float4*)(out + (long)n * 64 + lane * 4) = o;
  }
}

// Fused GAT layer, H=1 C=64, fp32 hs (bipartite): wave per node, lane=channel.
__global__ __launch_bounds__(256) void gat1_fused(
    int Nd, const int* __restrict__ dptr, const int* __restrict__ csr_src,
    const float* __restrict__ csr_ea, const float* __restrict__ al_s,
    const float* __restrict__ al_d, const float* __restrict__ dote,
    const float* __restrict__ hs, const float* __restrict__ bias,
    float* __restrict__ out) {
  int wave = threadIdx.x >> 6, lane = threadIdx.x & 63;
  int n = blockIdx.x * 4 + wave;
  if (n >= Nd) return;
  float ald = al_d[n];
  float de = dote[0];
  int e0 = dptr[n], e1 = dptr[n + 1];
  float m0 = -INFINITY, d0 = 0.f, acc0 = 0.f;
  float m1 = -INFINITY, d1 = 0.f, acc1 = 0.f;
  int e = e0;
  for (; e + 2 <= e1; e += 2) {
    int s0 = csr_src[e], s1 = csr_src[e + 1];
    float l0 = al_s[s0] + ald + csr_ea[e] * de;
    float l1 = al_s[s1] + ald + csr_ea[e + 1] * de;
    l0 = (l0 > 0.f) ? l0 : 0.2f * l0;
    l1 = (l1 > 0.f) ? l1 : 0.2f * l1;
    float h0 = hs[(long)s0 * 64 + lane];
    float h1 = hs[(long)s1 * 64 + lane];
    if (l0 > m0) { float sc = __expf(m0 - l0); d0 *= sc; acc0 *= sc; m0 = l0; }
    float ex0 = __expf(l0 - m0);
    d0 += ex0; acc0 = fmaf(ex0, h0, acc0);
    if (l1 > m1) { float sc = __expf(m1 - l1); d1 *= sc; acc1 *= sc; m1 = l1; }
    float ex1 = __expf(l1 - m1);
    d1 += ex1; acc1 = fmaf(ex1, h1, acc1);
  }
  if (e < e1) {
    int s0 = csr_src[e];
    float l0 = al_s[s0] + ald + csr_ea[e] * de;
    l0 = (l0 > 0.f) ? l0 : 0.2f * l0;
    float h0 = hs[(long)s0 * 64 + lane];
    if (l0 > m0) { float sc = __expf(m0 - l0); d0 *= sc; acc0 *= sc; m0 = l0; }
    float ex0 = __expf(l0 - m0);
    d0 += ex0; acc0 = fmaf(ex0, h0, acc0);
  }
  if (m1 != -INFINITY) {
    float M = fmaxf(m0, m1);
    float sA = (m0 == -INFINITY) ? 0.f : __expf(m0 - M);
    float sB = __expf(m1 - M);
    d0 = d0 * sA + d1 * sB;
    acc0 = acc0 * sA + acc1 * sB;
  }
  float o = acc0 / (d0 + 1e-16f);
  out[(long)n * 64 + lane] = fmaxf(o + bias[lane], 0.f);
}

// ---------------------------------------------------------------------------
extern "C" void kernel_launch(void* const* d_in, const int* in_sizes, int n_in,
                              void* d_out, int out_size, void* d_ws, size_t ws_size,
                              hipStream_t stream) {
  const float* sp_mean = (const float*)d_in[0];
  const float* sp_std  = (const float*)d_in[1];
  const void*  nanmask = d_in[2];
  const float* sp_gen  = (const float*)d_in[3];
  const float* sp_phy  = (const float*)d_in[4];
  const float* spat_x  = (const float*)d_in[5];
  const float* spat_g  = (const float*)d_in[6];
  const int*   ss_ei   = (const int*)d_in[7];
  const float* ss_ea   = (const float*)d_in[8];
  const int*   bip_ei  = (const int*)d_in[9];
  const float* bip_ea  = (const float*)d_in[10];
  const int*   sp_ei   = (const int*)d_in[11];
  const float* sp_ea   = (const float*)d_in[12];
  const float* sg0_W = (const float*)d_in[13]; const float* sg0_as = (const float*)d_in[14];
  const float* sg0_ad = (const float*)d_in[15]; const float* sg0_ae = (const float*)d_in[16];
  const float* sg0_We = (const float*)d_in[17]; const float* sg0_b = (const float*)d_in[18];
  const float* sg1_W = (const float*)d_in[19]; const float* sg1_as = (const float*)d_in[20];
  const float* sg1_ad = (const float*)d_in[21]; const float* sg1_ae = (const float*)d_in[22];
  const float* sg1_We = (const float*)d_in[23]; const float* sg1_b = (const float*)d_in[24];
  const float* pg0_W = (const float*)d_in[25]; const float* pg0_as = (const float*)d_in[26];
  const float* pg0_ad = (const float*)d_in[27]; const float* pg0_ae = (const float*)d_in[28];
  const float* pg0_We = (const float*)d_in[29]; const float* pg0_b = (const float*)d_in[30];
  const float* pg1_W = (const float*)d_in[31]; const float* pg1_as = (const float*)d_in[32];
  const float* pg1_ad = (const float*)d_in[33]; const float* pg1_ae = (const float*)d_in[34];
  const float* pg1_We = (const float*)d_in[35]; const float* pg1_b = (const float*)d_in[36];
  const float* bp_Ws = (const float*)d_in[37]; const float* bp_Wd = (const float*)d_in[38];
  const float* bp_as = (const float*)d_in[39]; const float* bp_ad = (const float*)d_in[40];
  const float* bp_ae = (const float*)d_in[41]; const float* bp_We = (const float*)d_in[42];
  const float* bp_b  = (const float*)d_in[43];
  const float* sl_W  = (const float*)d_in[44]; const float* sl_b  = (const float*)d_in[45];
  const float* fc_W  = (const float*)d_in[46]; const float* fc_b  = (const float*)d_in[47];

  // ---- workspace layout ----
  char* wsb = (char*)d_ws;
  size_t off = 0;
  auto A = [&](size_t nbytes) -> void* {
    void* p = wsb + off;
    off += (nbytes + 255) & ~(size_t)255;
    return p;
  };
  // --- zeroed region (single memset): partitioned counters ---
  int* ss_cp = (int*)A((size_t)8 * NSPAT * 4);
  int* bp_cp = (int*)A((size_t)8 * NSP * 4);
  int* pp_cp = (int*)A((size_t)8 * NSP * 4);
  size_t zbytes = off;
  // --- rest ---
  int*   ss_cnt = (int*)A((NSPAT + 1) * 4);
  int*   bp_cnt = (int*)A((NSP + 1) * 4);
  int*   pp_cnt = (int*)A((NSP + 1) * 4);
  int*   flag  = (int*)A(4);
  float* dotes = (float*)A(5 * 4 * sizeof(float));
  float* alS   = (float*)A((size_t)NSP * 4 * 4);
  float* alD   = (float*)A((size_t)NSP * 4 * 4);
  float* spc96 = (float*)A((size_t)NSP * 96 * 4);
  float* sp_in = (float*)A((size_t)NSP * 64 * 4);
  float* h0    = (float*)A((size_t)NSPAT * 16 * 4);
  float* h_a   = (float*)A((size_t)NSPAT * 64 * 4);
  float* h_b   = (float*)A((size_t)NSPAT * 64 * 4);
  float* HS    = (float*)A((size_t)NSP * 256 * 4);   // bf16 hs rows
  float* sts   = (float*)A((size_t)NSP * 64 * 4);
  float* x1    = (float*)A((size_t)NSP * 64 * 4);
  int*   ss_ptr = (int*)A((NSPAT + 1) * 4);
  int*   ss_src = (int*)A((size_t)ESS * 4);
  float* ss_cea = (float*)A((size_t)ESS * 4);
  int*   ss_rnk = (int*)A((size_t)ESS * 4);
  float* ss_lea = (float*)A((size_t)NSPAT * 4);
  int*   bp_ptr = (int*)A((NSP + 1) * 4);
  int*   bp_src = (int*)A((size_t)EBIP * 4);
  float* bp_cea = (float*)A((size_t)EBIP * 4);
  int*   bp_rnk = (int*)A((size_t)EBIP * 4);
  int*   pp_ptr = (int*)A((NSP + 1) * 4);
  int*   pp_src = (int*)A((size_t)ESP * 4);
  float* pp_cea = (float*)A((size_t)ESP * 4);
  int*   pp_rnk = (int*)A((size_t)ESP * 4);
  float* pp_lea = (float*)A((size_t)NSP * 4);
  (void)ws_size; (void)in_sizes; (void)n_in; (void)out_size;

  const int TB = 256;
  hipMemsetAsync(wsb, 0, zbytes, stream);

  // ---- graph builds: partitioned count -> merge -> scan -> scatter ----
  count3_kernel<<<cdiv_host(ESS + EBIP + ESP, TB), TB, 0, stream>>>(
      ss_ei + ESS, ESS, ss_cp, ss_rnk, NSPAT,
      bip_ei + EBIP, EBIP, bp_cp, bp_rnk, NSP,
      sp_ei + ESP, ESP, pp_cp, pp_rnk, NSP);
  merge3_kernel<<<cdiv_host(NSPAT + NSP + NSP, TB), TB, 0, stream>>>(
      ss_cp, ss_cnt, NSPAT, bp_cp, bp_cnt, NSP, pp_cp, pp_cnt, NSP);
  scan3_kernel<<<3, 1024, 0, stream>>>(ss_cnt, NSPAT, ss_ptr, bp_cnt, NSP, bp_ptr, pp_cnt, NSP, pp_ptr);
  scatter3_kernel<<<cdiv_host(ESS + EBIP + ESP, TB), TB, 0, stream>>>(
      ss_ei, ss_ei + ESS, ss_ea, ESS, ss_ptr, ss_cp, ss_rnk, NSPAT, ss_src, ss_cea,
      bip_ei, bip_ei + EBIP, bip_ea, EBIP, bp_ptr, bp_cp, bp_rnk, NSP, bp_src, bp_cea,
      sp_ei, sp_ei + ESP, sp_ea, ESP, pp_ptr, pp_cp, pp_rnk, NSP, pp_src, pp_cea);
  leafin_csr2<<<cdiv_host(NSPAT + NSP, TB), TB, 0, stream>>>(
      ss_ptr, ss_cea, NSPAT, ss_lea, pp_ptr, pp_cea, NSP, pp_lea);

  dote_all_kernel<<<6, 256, 0, stream>>>(sg0_We, sg0_ae, sg1_We, sg1_ae, bp_We, bp_ae,
                                         pg0_We, pg0_ae, pg1_We, pg1_ae,
                                         (const unsigned int*)nanmask, dotes, flag);

  // ---- prep: spc96 + h0 in one launch ----
  build_pre_kernel<<<cdiv_host((long)NSP * 96 + (long)NSPAT * 16, TB), TB, 0, stream>>>(
      sp_mean, sp_std, nanmask, flag, spat_x, spat_g, spc96, h0);

  // ---- species input MLP ----
  {
    XSrc xs{}; xs.p[0] = spc96; xs.w[0] = 96; xs.p[1] = sp_gen; xs.w[1] = 64;
    xs.p[2] = sp_phy; xs.w[2] = 128; xs.n = 3;
    proj64_kernel<<<cdiv_host(NSP, 32), TB, 0, stream>>>(xs, NSP, 288, sl_W, sl_b, 1,
        nullptr, nullptr, nullptr, nullptr, sp_in, nullptr);
  }

  // ---- spatial GNN ----
  {
    XSrc xs{}; xs.p[0] = h0; xs.w[0] = 16; xs.n = 1;
    proj_kernel<<<cdiv_host(NSPAT, 32), TB, 0, stream>>>(xs, NSPAT, 16, sg0_W, nullptr, 3,
        sg0_as, sg0_ad, alS, alD, HS, nullptr);
  }
  gat4_fused<true><<<cdiv_host(NSPAT, 4), TB, 0, stream>>>(
      NSPAT, ss_ptr, ss_src, ss_cea, alS, alD, dotes + 0, ss_lea,
      (const unsigned short*)HS, sg0_b, h_a);
  {
    XSrc xs{}; xs.p[0] = h_a; xs.w[0] = 64; xs.n = 1;
    proj_kernel<<<cdiv_host(NSPAT, 32), TB, 0, stream>>>(xs, NSPAT, 64, sg1_W, nullptr, 3,
        sg1_as, sg1_ad, alS, alD, HS, nullptr);
  }
  gat4_fused<true><<<cdiv_host(NSPAT, 4), TB, 0, stream>>>(
      NSPAT, ss_ptr, ss_src, ss_cea, alS, alD, dotes + 4, ss_lea,
      (const unsigned short*)HS, sg1_b, h_b);

  // ---- bipartite GAT (spatial -> species), H=1, concat ----
  {
    XSrc xs{}; xs.p[0] = h_b; xs.w[0] = 64; xs.n = 1;
    proj64_kernel<<<cdiv_host(NSPAT, 32), TB, 0, stream>>>(xs, NSPAT, 64, bp_Ws, nullptr, 0,
        bp_as, nullptr, alS, nullptr, h_a, nullptr);   // h_a := hs_src (fp32)
  }
  {
    XSrc xs{}; xs.p[0] = sp_gen; xs.w[0] = 64; xs.p[1] = sp_phy; xs.w[1] = 128; xs.n = 2;
    proj64_kernel<<<cdiv_host(NSP, 32), TB, 0, stream>>>(xs, NSP, 192, bp_Wd, nullptr, 0,
        nullptr, bp_ad, nullptr, alD, nullptr, nullptr);   // only al_d needed
  }
  gat1_fused<<<cdiv_host(NSP, 4), TB, 0, stream>>>(
      NSP, bp_ptr, bp_src, bp_cea, alS, alD, dotes + 8, h_a, bp_b, sts);

  // ---- species GNN ----
  {
    XSrc xs{}; xs.p[0] = sts; xs.w[0] = 64; xs.p[1] = sp_in; xs.w[1] = 64; xs.n = 2;
    proj_kernel<<<cdiv_host(NSP, 32), TB, 0, stream>>>(xs, NSP, 128, pg0_W, nullptr, 3,
        pg0_as, pg0_ad, alS, alD, HS, nullptr);
  }
  gat4_fused<true><<<cdiv_host(NSP, 4), TB, 0, stream>>>(
      NSP, pp_ptr, pp_src, pp_cea, alS, alD, dotes + 12, pp_lea,
      (const unsigned short*)HS, pg0_b, x1);
  {
    XSrc xs{}; xs.p[0] = x1; xs.w[0] = 64; xs.n = 1;
    proj_kernel<<<cdiv_host(NSP, 32), TB, 0, stream>>>(xs, NSP, 64, pg1_W, nullptr, 3,
        pg1_as, pg1_ad, alS, alD, HS, nullptr);
  }
  gat4_fused<true><<<cdiv_host(NSP, 4), TB, 0, stream>>>(
      NSP, pp_ptr, pp_src, pp_cea, alS, alD, dotes + 16, pp_lea,
      (const unsigned short*)HS, pg1_b, sts);   // sts := x2

  // ---- final linear fused with split/softplus ----
  {
    XSrc xs{}; xs.p[0] = sts; xs.w[0] = 64; xs.n = 1;
    proj64_kernel<<<cdiv_host(NSP, 32), TB, 0, stream>>>(xs, NSP, 64, fc_W, fc_b, 2,
        nullptr, nullptr, nullptr, nullptr, (float*)d_out, (float*)d_out + (long)NSP * 32);
  }
}

// Round 12
// 498.255 us; speedup vs baseline: 1.3185x; 1.0534x over previous
//
#include <hip/hip_runtime.h>
#include <hip/hip_bf16.h>

#define NSP   20000
#define NSPAT 10000
#define ESS   160000
#define EBIP  320000
#define ESP   320000

static inline int cdiv_host(long a, long b) { return (int)((a + b - 1) / b); }

__device__ __forceinline__ float wave_red_sum(float p) {
#pragma unroll
  for (int m = 32; m >= 1; m >>= 1) p += __shfl_xor(p, m, 64);
  return p;
}

__device__ __forceinline__ float bf2f(unsigned short u) {
  return __uint_as_float(((unsigned int)u) << 16);
}
__device__ __forceinline__ unsigned short f2bf(float f) {
  unsigned int u = __float_as_uint(f);
  unsigned int r = (u + 0x7FFF + ((u >> 16) & 1)) >> 16;  // RN-even
  return (unsigned short)r;
}

// ---------------------------------------------------------------------------
// CSR count, 8-way partitioned atomics + mask-format detect (last block).
// Grid = 3126: blocks 0..3124 cover exactly ESS+EBIP+ESP edges.
// ---------------------------------------------------------------------------
__global__ void count3_kernel(
    const int* c1, int E1, int* cp1, int* rnk1, int n1,
    const int* c2, int E2, int* cp2, int* rnk2, int n2,
    const int* c3, int E3, int* cp3, int* rnk3, int n3,
    const unsigned int* __restrict__ mask, int* __restrict__ flag) {
  int b = blockIdx.x, t = threadIdx.x;
  if (b == gridDim.x - 1) {
    if (t < 64) {
      unsigned int w0 = mask[t], w1 = mask[t + 64], w2 = mask[t + 128], w3 = mask[t + 192];
      bool ai = (w0 <= 1u) && (w1 <= 1u) && (w2 <= 1u) && (w3 <= 1u);
      auto okf = [](unsigned int w) { return w == 0u || w == 0x3f800000u; };
      bool af = okf(w0) && okf(w1) && okf(w2) && okf(w3);
      unsigned long long bi = __ballot(ai), bf = __ballot(af);
      if (t == 0) *flag = (bi == ~0ull) ? 0 : ((bf == ~0ull) ? 2 : 1);
    }
    return;
  }
  int i = b * 256 + t;
  int total = E1 + E2 + E3;
  if (i >= total) return;
  int p = (i >> 8) & 7;
  if (i < E1) {
    int d = c1[i]; rnk1[i] = atomicAdd(&cp1[p * n1 + d], 1);
  } else if (i < E1 + E2) {
    int j = i - E1;
    int d = c2[j]; rnk2[j] = atomicAdd(&cp2[p * n2 + d], 1);
  } else {
    int j = i - E1 - E2;
    int d = c3[j]; rnk3[j] = atomicAdd(&cp3[p * n3 + d], 1);
  }
}

// parallel per-node partition merge: cp[p*n+d] -> per-partition exclusive
// offsets; cnt[d] = node total.  1 thread per node, coalesced per partition.
__global__ void merge3_kernel(int* cp1, int* c1, int n1,
                              int* cp2, int* c2, int n2,
                              int* cp3, int* c3, int n3) {
  int i = blockIdx.x * blockDim.x + threadIdx.x;
  int total = n1 + n2 + n3;
  if (i >= total) return;
  int *cp, *c; int n, d;
  if (i < n1) { cp = cp1; c = c1; n = n1; d = i; }
  else if (i < n1 + n2) { cp = cp2; c = c2; n = n2; d = i - n1; }
  else { cp = cp3; c = c3; n = n3; d = i - n1 - n2; }
  int s = 0;
#pragma unroll
  for (int p = 0; p < 8; ++p) { int t = cp[p * n + d]; cp[p * n + d] = s; s += t; }
  c[d] = s;
}

__global__ __launch_bounds__(1024) void scan3_kernel(
    const int* cntA, int nA, int* ptrA,
    const int* cntB, int nB, int* ptrB,
    const int* cntC, int nC, int* ptrC) {
  const int* cnt; int n; int* ptr;
  if (blockIdx.x == 0) { cnt = cntA; n = nA; ptr = ptrA; }
  else if (blockIdx.x == 1) { cnt = cntB; n = nB; ptr = ptrB; }
  else { cnt = cntC; n = nC; ptr = ptrC; }
  __shared__ int part[1024];
  int t = threadIdx.x;
  int ch = (n + 1023) / 1024;
  int beg = t * ch, end = min(beg + ch, n);
  int s = 0;
  for (int i = beg; i < end; ++i) s += cnt[i];
  part[t] = s;
  __syncthreads();
  for (int off = 1; off < 1024; off <<= 1) {
    int v = (t >= off) ? part[t - off] : 0;
    __syncthreads();
    part[t] += v;
    __syncthreads();
  }
  int run = (t == 0) ? 0 : part[t - 1];
  for (int i = beg; i < end; ++i) { ptr[i] = run; run += cnt[i]; }
  if (t == 1023) ptr[n] = part[1023];
}

__global__ void scatter3_kernel(
    const int* r1, const int* c1, const float* e1, int E1, const int* p1, const int* cp1, const int* k1, int n1, int* s1, float* a1,
    const int* r2, const int* c2, const float* e2, int E2, const int* p2, const int* cp2, const int* k2, int n2, int* s2, float* a2,
    const int* r3, const int* c3, const float* e3, int E3, const int* p3, const int* cp3, const int* k3, int n3, int* s3, float* a3) {
  int total = E1 + E2 + E3;
  for (int i = blockIdx.x * blockDim.x + threadIdx.x; i < total; i += gridDim.x * blockDim.x) {
    int p = (i >> 8) & 7;
    if (i < E1) {
      int d = c1[i];
      int pos = p1[d] + cp1[p * n1 + d] + k1[i];
      s1[pos] = r1[i]; a1[pos] = e1[i];
    } else if (i < E1 + E2) {
      int j = i - E1;
      int d = c2[j];
      int pos = p2[d] + cp2[p * n2 + d] + k2[j];
      s2[pos] = r2[j]; a2[pos] = e2[j];
    } else {
      int j = i - E1 - E2;
      int d = c3[j];
      int pos = p3[d] + cp3[p * n3 + d] + k3[j];
      s3[pos] = r3[j]; a3[pos] = e3[j];
    }
  }
}

// ---------------------------------------------------------------------------
// fused misc: blocks [0,118) leafin (loop_ea from CSR cea);
// blocks [118,123) dote per layer; blocks [123,8248) build spc96 + h0.
// ---------------------------------------------------------------------------
__global__ void misc_kernel(
    const int* __restrict__ ss_ptr, const float* __restrict__ ss_cea, float* __restrict__ ss_lea,
    const int* __restrict__ pp_ptr, const float* __restrict__ pp_cea, float* __restrict__ pp_lea,
    const float* __restrict__ We0, const float* __restrict__ ae0,
    const float* __restrict__ We1, const float* __restrict__ ae1,
    const float* __restrict__ Web, const float* __restrict__ aeb,
    const float* __restrict__ We2, const float* __restrict__ ae2,
    const float* __restrict__ We3, const float* __restrict__ ae3,
    float* __restrict__ dotes,
    const float* __restrict__ mean, const float* __restrict__ stdv,
    const void* __restrict__ mask, const int* __restrict__ flag,
    const float* __restrict__ sx, const float* __restrict__ sg,
    float* __restrict__ spc96, float* __restrict__ h0) {
  int b = blockIdx.x, t = threadIdx.x;
  if (b < 118) {
    int i = b * 256 + t;
    if (i >= NSPAT + NSP) return;
    const int* ptr; const float* cea; float* lea; int d;
    if (i < NSPAT) { ptr = ss_ptr; cea = ss_cea; lea = ss_lea; d = i; }
    else { ptr = pp_ptr; cea = pp_cea; lea = pp_lea; d = i - NSPAT; }
    int e0 = ptr[d], e1 = ptr[d + 1];
    float s = 0.f;
    for (int e = e0; e < e1; ++e) s += cea[e];
    lea[d] = s / (float)max(e1 - e0, 1);
  } else if (b < 123) {
    int lb = b - 118;
    const float *We, *ae; int n, off;
    switch (lb) {
      case 0: We = We0; ae = ae0; n = 256; off = 0; break;
      case 1: We = We1; ae = ae1; n = 256; off = 4; break;
      case 2: We = Web; ae = aeb; n = 64;  off = 8; break;
      case 3: We = We2; ae = ae2; n = 256; off = 12; break;
      default: We = We3; ae = ae3; n = 256; off = 16; break;
    }
    if (t < n) {
      float p = wave_red_sum(We[t] * ae[t]);
      if ((t & 63) == 0) dotes[off + (t >> 6)] = p;
    }
  } else {
    const long totA = (long)NSP * 96;
    const long totB = (long)NSPAT * 16;
    long i = (long)(b - 123) * 256 + t;
    if (i >= totA + totB) return;
    int mode = *flag;
    if (i < totA) {
      int n = (int)(i / 96), c = (int)(i % 96);
      float v;
      if (c < 32) v = mean[(long)n * 32 + c];
      else if (c < 64) v = stdv[(long)n * 32 + (c - 32)];
      else {
        long j = (long)n * 32 + (c - 64);
        int mv;
        if (mode == 0) mv = ((const int*)mask)[j];
        else if (mode == 2) mv = (((const float*)mask)[j] != 0.0f);
        else mv = (int)((const unsigned char*)mask)[j];
        v = mv ? 0.f : 1.f;   // vis = ~mask
      }
      spc96[i] = v;
    } else {
      long k = i - totA;
      int n = (int)(k / 16), c = (int)(k % 16);
      h0[k] = (c < 12) ? sx[(long)n * 12 + c] : sg[(long)n * 4 + (c - 12)];
    }
  }
}

struct XSrc { const float* p[5]; int w[5]; int n; };
struct PJob {
  XSrc xs; int M, K;
  const float* W; const float* bias; int mode;
  const float* a_s; const float* a_d;
  float* al_s; float* al_d;
  float* Y; float* Y2;
};

// ---------------------------------------------------------------------------
// NOUT=64 projection body, tiled: BR=32 rows/block, KC=32.  4 cols x 2 rows
// per thread.  mode: 0 = bias (skip store if Y null), 1 = bias+relu,
// 2 = final split (mean | softplus+eps).  a_s/a_d: H=1 dots.
// ---------------------------------------------------------------------------
__device__ __forceinline__ void proj64_body(const PJob& J, int bid,
                                            float* wl, float* xl) {
  constexpr int KC = 32;
  constexpr int BR = 32;
  constexpr int KCP = 36;
  int t = threadIdx.x;
  long row0 = (long)bid * BR;
  if (row0 >= J.M) return;
  int cg = t & 15, rg = t >> 4;
  int c0 = cg * 4;

  float acc[2][4];
#pragma unroll
  for (int r = 0; r < 2; ++r)
#pragma unroll
    for (int j = 0; j < 4; ++j) acc[r][j] = 0.f;

  for (int k0 = 0; k0 < J.K; k0 += KC) {
    int seg = 0; int base = 0;
    while (k0 >= base + J.xs.w[seg]) { base += J.xs.w[seg]; ++seg; }
    const float* Xp = J.xs.p[seg];
    int stride = J.xs.w[seg];
    int kloc = k0 - base;

    __syncthreads();
    {
      const float4* ws = (const float4*)(J.W + (long)k0 * 64);
      float4* wd = (float4*)wl;
      wd[t] = ws[t];
      wd[t + 256] = ws[t + 256];
    }
    {
      int r = t >> 3, kq = (t & 7) * 4;
      long rr = row0 + r; if (rr >= J.M) rr = J.M - 1;
      float4 v = *(const float4*)(Xp + rr * stride + kloc + kq);
      *(float4*)(xl + r * KCP + kq) = v;
    }
    __syncthreads();

    for (int kg = 0; kg < KC; kg += 4) {
      float4 w0 = *(const float4*)(wl + (kg + 0) * 64 + c0);
      float4 w1 = *(const float4*)(wl + (kg + 1) * 64 + c0);
      float4 w2 = *(const float4*)(wl + (kg + 2) * 64 + c0);
      float4 w3 = *(const float4*)(wl + (kg + 3) * 64 + c0);
#pragma unroll
      for (int r = 0; r < 2; ++r) {
        float4 xv = *(const float4*)(xl + (rg * 2 + r) * KCP + kg);
        acc[r][0] = fmaf(xv.x, w0.x, acc[r][0]);
        acc[r][1] = fmaf(xv.x, w0.y, acc[r][1]);
        acc[r][2] = fmaf(xv.x, w0.z, acc[r][2]);
        acc[r][3] = fmaf(xv.x, w0.w, acc[r][3]);
        acc[r][0] = fmaf(xv.y, w1.x, acc[r][0]);
        acc[r][1] = fmaf(xv.y, w1.y, acc[r][1]);
        acc[r][2] = fmaf(xv.y, w1.z, acc[r][2]);
        acc[r][3] = fmaf(xv.y, w1.w, acc[r][3]);
        acc[r][0] = fmaf(xv.z, w2.x, acc[r][0]);
        acc[r][1] = fmaf(xv.z, w2.y, acc[r][1]);
        acc[r][2] = fmaf(xv.z, w2.z, acc[r][2]);
        acc[r][3] = fmaf(xv.z, w2.w, acc[r][3]);
        acc[r][0] = fmaf(xv.w, w3.x, acc[r][0]);
        acc[r][1] = fmaf(xv.w, w3.y, acc[r][1]);
        acc[r][2] = fmaf(xv.w, w3.z, acc[r][2]);
        acc[r][3] = fmaf(xv.w, w3.w, acc[r][3]);
      }
    }
  }

  float4 bv = make_float4(0.f, 0.f, 0.f, 0.f);
  float4 asv = make_float4(0.f, 0.f, 0.f, 0.f);
  float4 adv = make_float4(0.f, 0.f, 0.f, 0.f);
  if (J.bias) bv = *(const float4*)(J.bias + c0);
  if (J.a_s) asv = *(const float4*)(J.a_s + c0);
  if (J.a_d) adv = *(const float4*)(J.a_d + c0);

#pragma unroll
  for (int r = 0; r < 2; ++r) {
    long m = row0 + rg * 2 + r;
    bool ok = m < J.M;
    float v0 = acc[r][0] + bv.x, v1 = acc[r][1] + bv.y;
    float v2 = acc[r][2] + bv.z, v3 = acc[r][3] + bv.w;
    if (J.mode == 1) {
      if (ok)
        *(float4*)(J.Y + m * 64 + c0) = make_float4(
            fmaxf(v0, 0.f), fmaxf(v1, 0.f), fmaxf(v2, 0.f), fmaxf(v3, 0.f));
    } else if (J.mode == 2) {
      if (ok) {
        if (c0 < 32) {
          *(float4*)(J.Y + m * 32 + c0) = make_float4(v0, v1, v2, v3);
        } else {
          float4 o;
          o.x = fmaxf(v0, 0.f) + log1pf(__expf(-fabsf(v0))) + 1e-6f;
          o.y = fmaxf(v1, 0.f) + log1pf(__expf(-fabsf(v1))) + 1e-6f;
          o.z = fmaxf(v2, 0.f) + log1pf(__expf(-fabsf(v2))) + 1e-6f;
          o.w = fmaxf(v3, 0.f) + log1pf(__expf(-fabsf(v3))) + 1e-6f;
          *(float4*)(J.Y2 + m * 32 + (c0 - 32)) = o;
        }
      }
    } else if (ok && J.Y) {
      *(float4*)(J.Y + m * 64 + c0) = make_float4(v0, v1, v2, v3);
    }
    if (J.a_s) {
      float s = acc[r][0] * asv.x + acc[r][1] * asv.y + acc[r][2] * asv.z + acc[r][3] * asv.w;
      s += __shfl_xor(s, 1); s += __shfl_xor(s, 2);
      s += __shfl_xor(s, 4); s += __shfl_xor(s, 8);
      if (ok && cg == 0) J.al_s[m] = s;
    }
    if (J.a_d) {
      float s = acc[r][0] * adv.x + acc[r][1] * adv.y + acc[r][2] * adv.z + acc[r][3] * adv.w;
      s += __shfl_xor(s, 1); s += __shfl_xor(s, 2);
      s += __shfl_xor(s, 4); s += __shfl_xor(s, 8);
      if (ok && cg == 0) J.al_d[m] = s;
    }
  }
}

// two independent NOUT=64 jobs in one launch (blocks < nb0 -> j0, else j1)
__global__ __launch_bounds__(256) void proj64x2_kernel(PJob j0, PJob j1, int nb0) {
  __shared__ float wl[32 * 64];
  __shared__ float xl[32 * 36];
  if ((int)blockIdx.x < nb0) proj64_body(j0, blockIdx.x, wl, xl);
  else proj64_body(j1, blockIdx.x - nb0, wl, xl);
}

// ---------------------------------------------------------------------------
// NOUT=256 projection (tiled, BR=32): X and W staged in LDS.
// mode: 3 = store bf16 (used for all H=4 hs tables)
// ---------------------------------------------------------------------------
__global__ __launch_bounds__(256) void proj_kernel(
    XSrc xsrc, int M, int K,
    const float* __restrict__ W, const float* __restrict__ bias, int mode,
    const float* __restrict__ a_s, const float* __restrict__ a_d,
    float* __restrict__ al_s, float* __restrict__ al_d,
    float* __restrict__ Y, float* __restrict__ Y2) {
  constexpr int NOUT = 256;
  constexpr int KC = 32;
  constexpr int RPT = 8;
  constexpr int BR = 32;
  constexpr int KCP = 36;
  constexpr int H = 4;
  __shared__ float wl[KC * NOUT];
  __shared__ float xl[BR * KCP];

  int t = threadIdx.x;
  int cg = t & 63, rg = t >> 6;
  int c0 = cg * 4;
  long row0 = (long)blockIdx.x * BR;

  float acc[RPT][4];
#pragma unroll
  for (int r = 0; r < RPT; ++r)
#pragma unroll
    for (int j = 0; j < 4; ++j) acc[r][j] = 0.f;

  for (int k0 = 0; k0 < K; k0 += KC) {
    int kc = min(KC, K - k0);
    int seg = 0; int base = 0;
    while (k0 >= base + xsrc.w[seg]) { base += xsrc.w[seg]; ++seg; }
    const float* Xp = xsrc.p[seg];
    int stride = xsrc.w[seg];
    int kloc = k0 - base;

    __syncthreads();
    {
      const float4* wsrc = (const float4*)(W + (long)k0 * NOUT);
      float4* wdst = (float4*)wl;
      for (int i = t; i < (kc * NOUT) >> 2; i += 256) wdst[i] = wsrc[i];
    }
    for (int i = t; i < BR * 8; i += 256) {
      int r = i >> 3, kq = (i & 7) * 4;
      if (kq < kc) {
        long rr = row0 + r; if (rr >= M) rr = M - 1;
        float4 v = *(const float4*)(Xp + rr * stride + kloc + kq);
        *(float4*)(xl + r * KCP + kq) = v;
      }
    }
    __syncthreads();

    for (int kg = 0; kg < kc; kg += 4) {
      float4 w0 = *(const float4*)(wl + (kg + 0) * NOUT + c0);
      float4 w1 = *(const float4*)(wl + (kg + 1) * NOUT + c0);
      float4 w2 = *(const float4*)(wl + (kg + 2) * NOUT + c0);
      float4 w3 = *(const float4*)(wl + (kg + 3) * NOUT + c0);
      float4 xv[RPT];
#pragma unroll
      for (int r = 0; r < RPT; ++r)
        xv[r] = *(const float4*)(xl + (rg * RPT + r) * KCP + kg);
#pragma unroll
      for (int r = 0; r < RPT; ++r) {
        acc[r][0] = fmaf(xv[r].x, w0.x, acc[r][0]);
        acc[r][1] = fmaf(xv[r].x, w0.y, acc[r][1]);
        acc[r][2] = fmaf(xv[r].x, w0.z, acc[r][2]);
        acc[r][3] = fmaf(xv[r].x, w0.w, acc[r][3]);
        acc[r][0] = fmaf(xv[r].y, w1.x, acc[r][0]);
        acc[r][1] = fmaf(xv[r].y, w1.y, acc[r][1]);
        acc[r][2] = fmaf(xv[r].y, w1.z, acc[r][2]);
        acc[r][3] = fmaf(xv[r].y, w1.w, acc[r][3]);
        acc[r][0] = fmaf(xv[r].z, w2.x, acc[r][0]);
        acc[r][1] = fmaf(xv[r].z, w2.y, acc[r][1]);
        acc[r][2] = fmaf(xv[r].z, w2.z, acc[r][2]);
        acc[r][3] = fmaf(xv[r].z, w2.w, acc[r][3]);
        acc[r][0] = fmaf(xv[r].w, w3.x, acc[r][0]);
        acc[r][1] = fmaf(xv[r].w, w3.y, acc[r][1]);
        acc[r][2] = fmaf(xv[r].w, w3.z, acc[r][2]);
        acc[r][3] = fmaf(xv[r].w, w3.w, acc[r][3]);
      }
    }
  }

  float4 asv = make_float4(0.f, 0.f, 0.f, 0.f);
  float4 adv = make_float4(0.f, 0.f, 0.f, 0.f);
  if (a_s) asv = *(const float4*)(a_s + c0);
  if (a_d) adv = *(const float4*)(a_d + c0);

#pragma unroll
  for (int r = 0; r < RPT; ++r) {
    long m = row0 + (long)rg * RPT + r;
    bool ok = m < M;
    if (ok && mode == 3) {
      ushort4 o;
      o.x = f2bf(acc[r][0]); o.y = f2bf(acc[r][1]);
      o.z = f2bf(acc[r][2]); o.w = f2bf(acc[r][3]);
      *(ushort4*)((unsigned short*)Y + m * NOUT + c0) = o;
    }
    if (a_s) {
      float s = acc[r][0] * asv.x + acc[r][1] * asv.y + acc[r][2] * asv.z + acc[r][3] * asv.w;
      s += __shfl_xor(s, 1); s += __shfl_xor(s, 2);
      s += __shfl_xor(s, 4); s += __shfl_xor(s, 8);
      if (ok && (cg & 15) == 0) al_s[m * H + (c0 >> 6)] = s;
    }
    if (a_d) {
      float s = acc[r][0] * adv.x + acc[r][1] * adv.y + acc[r][2] * adv.z + acc[r][3] * adv.w;
      s += __shfl_xor(s, 1); s += __shfl_xor(s, 2);
      s += __shfl_xor(s, 4); s += __shfl_xor(s, 8);
      if (ok && (cg & 15) == 0) al_d[m * H + (c0 >> 6)] = s;
    }
  }
  (void)bias; (void)Y2;
}

// ---------------------------------------------------------------------------
// Fused GAT layer, H=4 C=64, bf16 hs: one wave per node covers all heads.
// ---------------------------------------------------------------------------
__device__ __forceinline__ void fma4_bf(float4& a, float al, ushort4 u) {
  a.x = fmaf(al, bf2f(u.x), a.x); a.y = fmaf(al, bf2f(u.y), a.y);
  a.z = fmaf(al, bf2f(u.z), a.z); a.w = fmaf(al, bf2f(u.w), a.w);
}
__device__ __forceinline__ void scale4(float4& a, float s) {
  a.x *= s; a.y *= s; a.z *= s; a.w *= s;
}

template <bool SELFLOOP>
__global__ __launch_bounds__(256) void gat4_fused(
    int Nd, const int* __restrict__ dptr, const int* __restrict__ csr_src,
    const float* __restrict__ csr_ea, const float* __restrict__ al_s,
    const float* __restrict__ al_d, const float* __restrict__ dote,
    const float* __restrict__ loop_ea, const unsigned short* __restrict__ hs,
    const float* __restrict__ bias, float* __restrict__ out) {
  int wave = threadIdx.x >> 6, lane = threadIdx.x & 63;
  int n = blockIdx.x * 4 + wave;
  if (n >= Nd) return;
  int h = lane >> 4;
  float ald = al_d[(long)n * 4 + h];
  float de = dote[h];
  int e0 = dptr[n], e1 = dptr[n + 1];
  float m0 = -INFINITY, d0 = 0.f;
  float4 a0 = make_float4(0.f, 0.f, 0.f, 0.f);
  if (SELFLOOP) {
    float l = al_s[(long)n * 4 + h] + ald + loop_ea[n] * de;
    l = (l > 0.f) ? l : 0.2f * l;
    m0 = l; d0 = 1.f;
    ushort4 u = *(const ushort4*)(hs + (long)n * 256 + lane * 4);
    a0.x = bf2f(u.x); a0.y = bf2f(u.y); a0.z = bf2f(u.z); a0.w = bf2f(u.w);
  }
  float m1 = -INFINITY, d1 = 0.f;
  float4 a1 = make_float4(0.f, 0.f, 0.f, 0.f);
  int e = e0;
  for (; e + 2 <= e1; e += 2) {
    int s0 = csr_src[e], s1 = csr_src[e + 1];
    float l0 = al_s[(long)s0 * 4 + h] + ald + csr_ea[e] * de;
    float l1 = al_s[(long)s1 * 4 + h] + ald + csr_ea[e + 1] * de;
    l0 = (l0 > 0.f) ? l0 : 0.2f * l0;
    l1 = (l1 > 0.f) ? l1 : 0.2f * l1;
    ushort4 u0 = *(const ushort4*)(hs + (long)s0 * 256 + lane * 4);
    ushort4 u1 = *(const ushort4*)(hs + (long)s1 * 256 + lane * 4);
    if (l0 > m0) { float sc = __expf(m0 - l0); d0 *= sc; scale4(a0, sc); m0 = l0; }
    float ex0 = __expf(l0 - m0);
    d0 += ex0;
    fma4_bf(a0, ex0, u0);
    if (l1 > m1) { float sc = __expf(m1 - l1); d1 *= sc; scale4(a1, sc); m1 = l1; }
    float ex1 = __expf(l1 - m1);
    d1 += ex1;
    fma4_bf(a1, ex1, u1);
  }
  if (e < e1) {
    int s0 = csr_src[e];
    float l0 = al_s[(long)s0 * 4 + h] + ald + csr_ea[e] * de;
    l0 = (l0 > 0.f) ? l0 : 0.2f * l0;
    ushort4 u0 = *(const ushort4*)(hs + (long)s0 * 256 + lane * 4);
    if (l0 > m0) { float sc = __expf(m0 - l0); d0 *= sc; scale4(a0, sc); m0 = l0; }
    float ex0 = __expf(l0 - m0);
    d0 += ex0;
    fma4_bf(a0, ex0, u0);
  }
  if (m1 != -INFINITY) {
    float M = fmaxf(m0, m1);
    float sA = (m0 == -INFINITY) ? 0.f : __expf(m0 - M);
    float sB = __expf(m1 - M);
    d0 = d0 * sA + d1 * sB;
    a0.x = a0.x * sA + a1.x * sB; a0.y = a0.y * sA + a1.y * sB;
    a0.z = a0.z * sA + a1.z * sB; a0.w = a0.w * sA + a1.w * sB;
  }
  float inv = 1.f / (d0 + 1e-16f);
  scale4(a0, inv);
  a0.x += __shfl_xor(a0.x, 16); a0.y += __shfl_xor(a0.y, 16);
  a0.z += __shfl_xor(a0.z, 16); a0.w += __shfl_xor(a0.w, 16);
  a0.x += __shfl_xor(a0.x, 32); a0.y += __shfl_xor(a0.y, 32);
  a0.z += __shfl_xor(a0.z, 32); a0.w += __shfl_xor(a0.w, 32);
  if (lane < 16) {
    float4 b = *(const float4*)(bias + lane * 4);
    float4 o;
    o.x = fmaxf(a0.x * 0.25f + b.x, 0.f);
    o.y = fmaxf(a0.y * 0.25f + b.y, 0.f);
    o.z = fmaxf(a0.z * 0.25f + b.z, 0.f);
    o.w = fmaxf(a0.w * 0.25f + b.w, 0.f);
    *(float4*)(out + (long)n * 64 + lane * 4) = o;
  }
}

// Fused GAT layer, H=1 C=64, fp32 hs (bipartite): wave per node, lane=channel.
__global__ __launch_bounds__(256) void gat1_fused(
    int Nd, const int* __restrict__ dptr, const int* __restrict__ csr_src,
    const float* __restrict__ csr_ea, const float* __restrict__ al_s,
    const float* __restrict__ al_d, const float* __restrict__ dote,
    const float* __restrict__ hs, const float* __restrict__ bias,
    float* __restrict__ out) {
  int wave = threadIdx.x >> 6, lane = threadIdx.x & 63;
  int n = blockIdx.x * 4 + wave;
  if (n >= Nd) return;
  float ald = al_d[n];
  float de = dote[0];
  int e0 = dptr[n], e1 = dptr[n + 1];
  float m0 = -INFINITY, d0 = 0.f, acc0 = 0.f;
  float m1 = -INFINITY, d1 = 0.f, acc1 = 0.f;
  int e = e0;
  for (; e + 2 <= e1; e += 2) {
    int s0 = csr_src[e], s1 = csr_src[e + 1];
    float l0 = al_s[s0] + ald + csr_ea[e] * de;
    float l1 = al_s[s1] + ald + csr_ea[e + 1] * de;
    l0 = (l0 > 0.f) ? l0 : 0.2f * l0;
    l1 = (l1 > 0.f) ? l1 : 0.2f * l1;
    float h0 = hs[(long)s0 * 64 + lane];
    float h1 = hs[(long)s1 * 64 + lane];
    if (l0 > m0) { float sc = __expf(m0 - l0); d0 *= sc; acc0 *= sc; m0 = l0; }
    float ex0 = __expf(l0 - m0);
    d0 += ex0; acc0 = fmaf(ex0, h0, acc0);
    if (l1 > m1) { float sc = __expf(m1 - l1); d1 *= sc; acc1 *= sc; m1 = l1; }
    float ex1 = __expf(l1 - m1);
    d1 += ex1; acc1 = fmaf(ex1, h1, acc1);
  }
  if (e < e1) {
    int s0 = csr_src[e];
    float l0 = al_s[s0] + ald + csr_ea[e] * de;
    l0 = (l0 > 0.f) ? l0 : 0.2f * l0;
    float h0 = hs[(long)s0 * 64 + lane];
    if (l0 > m0) { float sc = __expf(m0 - l0); d0 *= sc; acc0 *= sc; m0 = l0; }
    float ex0 = __expf(l0 - m0);
    d0 += ex0; acc0 = fmaf(ex0, h0, acc0);
  }
  if (m1 != -INFINITY) {
    float M = fmaxf(m0, m1);
    float sA = (m0 == -INFINITY) ? 0.f : __expf(m0 - M);
    float sB = __expf(m1 - M);
    d0 = d0 * sA + d1 * sB;
    acc0 = acc0 * sA + acc1 * sB;
  }
  float o = acc0 / (d0 + 1e-16f);
  out[(long)n * 64 + lane] = fmaxf(o + bias[lane], 0.f);
}

// ---------------------------------------------------------------------------
extern "C" void kernel_launch(void* const* d_in, const int* in_sizes, int n_in,
                              void* d_out, int out_size, void* d_ws, size_t ws_size,
                              hipStream_t stream) {
  const float* sp_mean = (const float*)d_in[0];
  const float* sp_std  = (const float*)d_in[1];
  const void*  nanmask = d_in[2];
  const float* sp_gen  = (const float*)d_in[3];
  const float* sp_phy  = (const float*)d_in[4];
  const float* spat_x  = (const float*)d_in[5];
  const float* spat_g  = (const float*)d_in[6];
  const int*   ss_ei   = (const int*)d_in[7];
  const float* ss_ea   = (const float*)d_in[8];
  const int*   bip_ei  = (const int*)d_in[9];
  const float* bip_ea  = (const float*)d_in[10];
  const int*   sp_ei   = (const int*)d_in[11];
  const float* sp_ea   = (const float*)d_in[12];
  const float* sg0_W = (const float*)d_in[13]; const float* sg0_as = (const float*)d_in[14];
  const float* sg0_ad = (const float*)d_in[15]; const float* sg0_ae = (const float*)d_in[16];
  const float* sg0_We = (const float*)d_in[17]; const float* sg0_b = (const float*)d_in[18];
  const float* sg1_W = (const float*)d_in[19]; const float* sg1_as = (const float*)d_in[20];
  const float* sg1_ad = (const float*)d_in[21]; const float* sg1_ae = (const float*)d_in[22];
  const float* sg1_We = (const float*)d_in[23]; const float* sg1_b = (const float*)d_in[24];
  const float* pg0_W = (const float*)d_in[25]; const float* pg0_as = (const float*)d_in[26];
  const float* pg0_ad = (const float*)d_in[27]; const float* pg0_ae = (const float*)d_in[28];
  const float* pg0_We = (const float*)d_in[29]; const float* pg0_b = (const float*)d_in[30];
  const float* pg1_W = (const float*)d_in[31]; const float* pg1_as = (const float*)d_in[32];
  const float* pg1_ad = (const float*)d_in[33]; const float* pg1_ae = (const float*)d_in[34];
  const float* pg1_We = (const float*)d_in[35]; const float* pg1_b = (const float*)d_in[36];
  const float* bp_Ws = (const float*)d_in[37]; const float* bp_Wd = (const float*)d_in[38];
  const float* bp_as = (const float*)d_in[39]; const float* bp_ad = (const float*)d_in[40];
  const float* bp_ae = (const float*)d_in[41]; const float* bp_We = (const float*)d_in[42];
  const float* bp_b  = (const float*)d_in[43];
  const float* sl_W  = (const float*)d_in[44]; const float* sl_b  = (const float*)d_in[45];
  const float* fc_W  = (const float*)d_in[46]; const float* fc_b  = (const float*)d_in[47];

  // ---- workspace layout ----
  char* wsb = (char*)d_ws;
  size_t off = 0;
  auto A = [&](size_t nbytes) -> void* {
    void* p = wsb + off;
    off += (nbytes + 255) & ~(size_t)255;
    return p;
  };
  // --- zeroed region (single memset): partitioned counters ---
  int* ss_cp = (int*)A((size_t)8 * NSPAT * 4);
  int* bp_cp = (int*)A((size_t)8 * NSP * 4);
  int* pp_cp = (int*)A((size_t)8 * NSP * 4);
  size_t zbytes = off;
  // --- rest ---
  int*   ss_cnt = (int*)A((NSPAT + 1) * 4);
  int*   bp_cnt = (int*)A((NSP + 1) * 4);
  int*   pp_cnt = (int*)A((NSP + 1) * 4);
  int*   flag  = (int*)A(4);
  float* dotes = (float*)A(5 * 4 * sizeof(float));
  float* alS   = (float*)A((size_t)NSP * 4 * 4);
  float* alD   = (float*)A((size_t)NSP * 4 * 4);
  float* alSb  = (float*)A((size_t)NSPAT * 4);     // bipartite src dots
  float* alDb  = (float*)A((size_t)NSP * 4);       // bipartite dst dots
  float* spc96 = (float*)A((size_t)NSP * 96 * 4);
  float* sp_in = (float*)A((size_t)NSP * 64 * 4);
  float* h0    = (float*)A((size_t)NSPAT * 16 * 4);
  float* h_a   = (float*)A((size_t)NSPAT * 64 * 4);
  float* h_b   = (float*)A((size_t)NSPAT * 64 * 4);
  float* HS    = (float*)A((size_t)NSP * 256 * 4);   // bf16 hs rows
  float* sts   = (float*)A((size_t)NSP * 64 * 4);
  float* x1    = (float*)A((size_t)NSP * 64 * 4);
  int*   ss_ptr = (int*)A((NSPAT + 1) * 4);
  int*   ss_src = (int*)A((size_t)ESS * 4);
  float* ss_cea = (float*)A((size_t)ESS * 4);
  int*   ss_rnk = (int*)A((size_t)ESS * 4);
  float* ss_lea = (float*)A((size_t)NSPAT * 4);
  int*   bp_ptr = (int*)A((NSP + 1) * 4);
  int*   bp_src = (int*)A((size_t)EBIP * 4);
  float* bp_cea = (float*)A((size_t)EBIP * 4);
  int*   bp_rnk = (int*)A((size_t)EBIP * 4);
  int*   pp_ptr = (int*)A((NSP + 1) * 4);
  int*   pp_src = (int*)A((size_t)ESP * 4);
  float* pp_cea = (float*)A((size_t)ESP * 4);
  int*   pp_rnk = (int*)A((size_t)ESP * 4);
  float* pp_lea = (float*)A((size_t)NSP * 4);
  (void)ws_size; (void)in_sizes; (void)n_in; (void)out_size;

  const int TB = 256;
  hipMemsetAsync(wsb, 0, zbytes, stream);

  // ---- graph builds: count(+detect) -> merge -> scan -> scatter ----
  count3_kernel<<<cdiv_host(ESS + EBIP + ESP, TB) + 1, TB, 0, stream>>>(
      ss_ei + ESS, ESS, ss_cp, ss_rnk, NSPAT,
      bip_ei + EBIP, EBIP, bp_cp, bp_rnk, NSP,
      sp_ei + ESP, ESP, pp_cp, pp_rnk, NSP,
      (const unsigned int*)nanmask, flag);
  merge3_kernel<<<cdiv_host(NSPAT + NSP + NSP, TB), TB, 0, stream>>>(
      ss_cp, ss_cnt, NSPAT, bp_cp, bp_cnt, NSP, pp_cp, pp_cnt, NSP);
  scan3_kernel<<<3, 1024, 0, stream>>>(ss_cnt, NSPAT, ss_ptr, bp_cnt, NSP, bp_ptr, pp_cnt, NSP, pp_ptr);
  scatter3_kernel<<<cdiv_host(ESS + EBIP + ESP, TB), TB, 0, stream>>>(
      ss_ei, ss_ei + ESS, ss_ea, ESS, ss_ptr, ss_cp, ss_rnk, NSPAT, ss_src, ss_cea,
      bip_ei, bip_ei + EBIP, bip_ea, EBIP, bp_ptr, bp_cp, bp_rnk, NSP, bp_src, bp_cea,
      sp_ei, sp_ei + ESP, sp_ea, ESP, pp_ptr, pp_cp, pp_rnk, NSP, pp_src, pp_cea);

  // ---- fused misc: leafin + dote + spc96/h0 prep ----
  misc_kernel<<<123 + cdiv_host((long)NSP * 96 + (long)NSPAT * 16, TB), TB, 0, stream>>>(
      ss_ptr, ss_cea, ss_lea, pp_ptr, pp_cea, pp_lea,
      sg0_We, sg0_ae, sg1_We, sg1_ae, bp_We, bp_ae, pg0_We, pg0_ae, pg1_We, pg1_ae,
      dotes, sp_mean, sp_std, nanmask, flag, spat_x, spat_g, spc96, h0);

  // ---- sl proj + bp_Wd proj in one launch (both independent) ----
  {
    PJob j0{}; j0.xs.p[0] = spc96; j0.xs.w[0] = 96; j0.xs.p[1] = sp_gen; j0.xs.w[1] = 64;
    j0.xs.p[2] = sp_phy; j0.xs.w[2] = 128; j0.xs.n = 3;
    j0.M = NSP; j0.K = 288; j0.W = sl_W; j0.bias = sl_b; j0.mode = 1; j0.Y = sp_in;
    PJob j1{}; j1.xs.p[0] = sp_gen; j1.xs.w[0] = 64; j1.xs.p[1] = sp_phy; j1.xs.w[1] = 128;
    j1.xs.n = 2;
    j1.M = NSP; j1.K = 192; j1.W = bp_Wd; j1.mode = 0; j1.a_d = bp_ad; j1.al_d = alDb;
    int nb0 = cdiv_host(NSP, 32);
    proj64x2_kernel<<<nb0 + cdiv_host(NSP, 32), TB, 0, stream>>>(j0, j1, nb0);
  }

  // ---- spatial GNN ----
  {
    XSrc xs{}; xs.p[0] = h0; xs.w[0] = 16; xs.n = 1;
    proj_kernel<<<cdiv_host(NSPAT, 32), TB, 0, stream>>>(xs, NSPAT, 16, sg0_W, nullptr, 3,
        sg0_as, sg0_ad, alS, alD, HS, nullptr);
  }
  gat4_fused<true><<<cdiv_host(NSPAT, 4), TB, 0, stream>>>(
      NSPAT, ss_ptr, ss_src, ss_cea, alS, alD, dotes + 0, ss_lea,
      (const unsigned short*)HS, sg0_b, h_a);
  {
    XSrc xs{}; xs.p[0] = h_a; xs.w[0] = 64; xs.n = 1;
    proj_kernel<<<cdiv_host(NSPAT, 32), TB, 0, stream>>>(xs, NSPAT, 64, sg1_W, nullptr, 3,
        sg1_as, sg1_ad, alS, alD, HS, nullptr);
  }
  gat4_fused<true><<<cdiv_host(NSPAT, 4), TB, 0, stream>>>(
      NSPAT, ss_ptr, ss_src, ss_cea, alS, alD, dotes + 4, ss_lea,
      (const unsigned short*)HS, sg1_b, h_b);

  // ---- bipartite GAT (spatial -> species), H=1, concat ----
  {
    PJob j0{}; j0.xs.p[0] = h_b; j0.xs.w[0] = 64; j0.xs.n = 1;
    j0.M = NSPAT; j0.K = 64; j0.W = bp_Ws; j0.mode = 0;
    j0.a_s = bp_as; j0.al_s = alSb; j0.Y = h_a;    // h_a := hs_src (fp32)
    int nb0 = cdiv_host(NSPAT, 32);
    proj64x2_kernel<<<nb0, TB, 0, stream>>>(j0, j0, nb0);
  }
  gat1_fused<<<cdiv_host(NSP, 4), TB, 0, stream>>>(
      NSP, bp_ptr, bp_src, bp_cea, alSb, alDb, dotes + 8, h_a, bp_b, sts);

  // ---- species GNN ----
  {
    XSrc xs{}; xs.p[0] = sts; xs.w[0] = 64; xs.p[1] = sp_in; xs.w[1] = 64; xs.n = 2;
    proj_kernel<<<cdiv_host(NSP, 32), TB, 0, stream>>>(xs, NSP, 128, pg0_W, nullptr, 3,
        pg0_as, pg0_ad, alS, alD, HS, nullptr);
  }
  gat4_fused<true><<<cdiv_host(NSP, 4), TB, 0, stream>>>(
      NSP, pp_ptr, pp_src, pp_cea, alS, alD, dotes + 12, pp_lea,
      (const unsigned short*)HS, pg0_b, x1);
  {
    XSrc xs{}; xs.p[0] = x1; xs.w[0] = 64; xs.n = 1;
    proj_kernel<<<cdiv_host(NSP, 32), TB, 0, stream>>>(xs, NSP, 64, pg1_W, nullptr, 3,
        pg1_as, pg1_ad, alS, alD, HS, nullptr);
  }
  gat4_fused<true><<<cdiv_host(NSP, 4), TB, 0, stream>>>(
      NSP, pp_ptr, pp_src, pp_cea, alS, alD, dotes + 16, pp_lea,
      (const unsigned short*)HS, pg1_b, sts);   // sts := x2

  // ---- final linear fused with split/softplus ----
  {
    PJob j0{}; j0.xs.p[0] = sts; j0.xs.w[0] = 64; j0.xs.n = 1;
    j0.M = NSP; j0.K = 64; j0.W = fc_W; j0.bias = fc_b; j0.mode = 2;
    j0.Y = (float*)d_out; j0.Y2 = (float*)d_out + (long)NSP * 32;
    int nb0 = cdiv_host(NSP, 32);
    proj64x2_kernel<<<nb0, TB, 0, stream>>>(j0, j0, nb0);
  }
}